// Round 1
// baseline (6248.606 us; speedup 1.0000x reference)
//
#include <hip/hip_runtime.h>
#include <hip/hip_bf16.h>

// GCN: h1 = relu(GCNConv(x; W1,b1)); h2 = sigmoid(GCNConv(h1; W2,b2));
//      h3 = relu(h2@W3+b3); h4 = relu(h3@W4+b4); out = h4@W5+b5
//
// GCNConv refactor: out[d] = dinv[d] * ( sum_{s->d} h[s]*dinv[s] + h[d]*dinv[d]... )
//   exactly: acc[v] = h'[v] (self loop) + sum_{edges s->v} h'[s],  h' = h*dinv
//            out[v] = dinv[v]*acc[v] + b
// => edge loop needs NO dinv gathers: idx read + h' gather + atomic scatter only.

constexpr int NT = 256;

__global__ void k_deg(const int* __restrict__ dst, int* __restrict__ deg, int E) {
    int e = blockIdx.x * blockDim.x + threadIdx.x;
    if (e < E) atomicAdd(deg + dst[e], 1);
}

// dinv = rsqrt(deg+1); h1' = (x @ W1) * dinv ; acc1 init = h1' (self loop)
__global__ void k_node1(const float2* __restrict__ x, const int* __restrict__ deg,
                        const float* __restrict__ W1,
                        float* __restrict__ dinv, float4* __restrict__ hp,
                        float4* __restrict__ acc, int N) {
    int i = blockIdx.x * blockDim.x + threadIdx.x;
    if (i >= N) return;
    float2 xi = x[i];
    float di = rsqrtf((float)(deg[i] + 1));
    dinv[i] = di;
    float4 h;
    h.x = (xi.x * W1[0] + xi.y * W1[4]) * di;
    h.y = (xi.x * W1[1] + xi.y * W1[5]) * di;
    h.z = (xi.x * W1[2] + xi.y * W1[6]) * di;
    h.w = (xi.x * W1[3] + xi.y * W1[7]) * di;
    dinv[i] = di;
    hp[i] = h;
    acc[i] = h;
}

__global__ void k_agg4(const int* __restrict__ src, const int* __restrict__ dst,
                       const float4* __restrict__ hp, float* __restrict__ acc, int E) {
    int e = blockIdx.x * blockDim.x + threadIdx.x;
    if (e >= E) return;
    int s = src[e], d = dst[e];
    float4 h = hp[s];
    float* p = acc + ((size_t)d << 2);
    unsafeAtomicAdd(p + 0, h.x);
    unsafeAtomicAdd(p + 1, h.y);
    unsafeAtomicAdd(p + 2, h.z);
    unsafeAtomicAdd(p + 3, h.w);
}

// X1 = relu(dinv*acc1 + b1); h2' = (X1 @ W2) * dinv; overwrite bufA(h'), bufB(acc2 init)
__global__ void k_node2(const float* __restrict__ dinv,
                        const float* __restrict__ b1, const float* __restrict__ W2,
                        float4* __restrict__ bufA, float4* __restrict__ bufB, int N) {
    int i = blockIdx.x * blockDim.x + threadIdx.x;
    if (i >= N) return;
    float di = dinv[i];
    float4 a = bufB[i];
    float o0 = fmaxf(di * a.x + b1[0], 0.f);
    float o1 = fmaxf(di * a.y + b1[1], 0.f);
    float o2 = fmaxf(di * a.z + b1[2], 0.f);
    float o3 = fmaxf(di * a.w + b1[3], 0.f);
    float4 h;
    h.x = (o0 * W2[0] + o1 * W2[3] + o2 * W2[6] + o3 * W2[9]) * di;
    h.y = (o0 * W2[1] + o1 * W2[4] + o2 * W2[7] + o3 * W2[10]) * di;
    h.z = (o0 * W2[2] + o1 * W2[5] + o2 * W2[8] + o3 * W2[11]) * di;
    h.w = 0.f;
    bufA[i] = h;
    bufB[i] = h;
}

__global__ void k_agg3(const int* __restrict__ src, const int* __restrict__ dst,
                       const float4* __restrict__ hp, float* __restrict__ acc, int E) {
    int e = blockIdx.x * blockDim.x + threadIdx.x;
    if (e >= E) return;
    int s = src[e], d = dst[e];
    float4 h = hp[s];
    float* p = acc + ((size_t)d << 2);
    unsafeAtomicAdd(p + 0, h.x);
    unsafeAtomicAdd(p + 1, h.y);
    unsafeAtomicAdd(p + 2, h.z);
}

// X2 = sigmoid(dinv*acc2 + b2); MLP head; write out
__global__ void k_node3(const float* __restrict__ dinv, const float4* __restrict__ acc,
                        const float* __restrict__ b2,
                        const float* __restrict__ W3, const float* __restrict__ b3,
                        const float* __restrict__ W4, const float* __restrict__ b4,
                        const float* __restrict__ W5, const float* __restrict__ b5,
                        float* __restrict__ out, int N) {
    int i = blockIdx.x * blockDim.x + threadIdx.x;
    if (i >= N) return;
    float di = dinv[i];
    float4 a = acc[i];
    float z0 = di * a.x + b2[0];
    float z1 = di * a.y + b2[1];
    float z2 = di * a.z + b2[2];
    float s0 = 1.f / (1.f + expf(-z0));
    float s1 = 1.f / (1.f + expf(-z1));
    float s2 = 1.f / (1.f + expf(-z2));
    // W3: [3,4]
    float t0 = fmaxf(s0 * W3[0] + s1 * W3[4] + s2 * W3[8]  + b3[0], 0.f);
    float t1 = fmaxf(s0 * W3[1] + s1 * W3[5] + s2 * W3[9]  + b3[1], 0.f);
    float t2 = fmaxf(s0 * W3[2] + s1 * W3[6] + s2 * W3[10] + b3[2], 0.f);
    float t3 = fmaxf(s0 * W3[3] + s1 * W3[7] + s2 * W3[11] + b3[3], 0.f);
    // W4: [4,3]
    float u0 = fmaxf(t0 * W4[0] + t1 * W4[3] + t2 * W4[6] + t3 * W4[9]  + b4[0], 0.f);
    float u1 = fmaxf(t0 * W4[1] + t1 * W4[4] + t2 * W4[7] + t3 * W4[10] + b4[1], 0.f);
    float u2 = fmaxf(t0 * W4[2] + t1 * W4[5] + t2 * W4[8] + t3 * W4[11] + b4[2], 0.f);
    out[i] = u0 * W5[0] + u1 * W5[1] + u2 * W5[2] + b5[0];
}

extern "C" void kernel_launch(void* const* d_in, const int* in_sizes, int n_in,
                              void* d_out, int out_size, void* d_ws, size_t ws_size,
                              hipStream_t stream) {
    const float* x  = (const float*)d_in[0];
    const int*   ei = (const int*)d_in[1];
    const float* W1 = (const float*)d_in[2];
    const float* b1 = (const float*)d_in[3];
    const float* W2 = (const float*)d_in[4];
    const float* b2 = (const float*)d_in[5];
    const float* W3 = (const float*)d_in[6];
    const float* b3 = (const float*)d_in[7];
    const float* W4 = (const float*)d_in[8];
    const float* b4 = (const float*)d_in[9];
    const float* W5 = (const float*)d_in[10];
    const float* b5 = (const float*)d_in[11];

    const int N = in_sizes[0] / 2;   // x is [N,2]
    const int E = in_sizes[1] / 2;   // edge_index is [2,E]
    const int* src = ei;
    const int* dst = ei + E;

    char* ws = (char*)d_ws;
    int*    deg  = (int*)ws;                                  // N * 4B
    float*  dinv = (float*)(ws + (size_t)N * 4);              // N * 4B
    float4* bufA = (float4*)(ws + (size_t)N * 8);             // N * 16B : h1' then h2'
    float4* bufB = (float4*)(ws + (size_t)N * 8 + (size_t)N * 16); // N * 16B : acc1 then acc2
    // total ws use: 40 * N bytes = 40 MB

    const int gbE = (E + NT - 1) / NT;
    const int gbN = (N + NT - 1) / NT;

    hipMemsetAsync(deg, 0, (size_t)N * 4, stream);
    k_deg  <<<gbE, NT, 0, stream>>>(dst, deg, E);
    k_node1<<<gbN, NT, 0, stream>>>((const float2*)x, deg, W1, dinv, bufA, bufB, N);
    k_agg4 <<<gbE, NT, 0, stream>>>(src, dst, bufA, (float*)bufB, E);
    k_node2<<<gbN, NT, 0, stream>>>(dinv, b1, W2, bufA, bufB, N);
    k_agg3 <<<gbE, NT, 0, stream>>>(src, dst, bufA, (float*)bufB, E);
    k_node3<<<gbN, NT, 0, stream>>>(dinv, bufB, b2, W3, b3, W4, b4, W5, b5,
                                    (float*)d_out, N);
}

// Round 2
// 2381.755 us; speedup vs baseline: 2.6235x; 2.6235x over previous
//
#include <hip/hip_runtime.h>
#include <hip/hip_bf16.h>

// GCN via counting-sort CSR:
//   deg histogram -> exclusive scan -> scatter (src sorted by dst) ->
//   gather-only aggregation per node (no float atomics), epilogues fused.
// GCNConv algebra: hp = (h@W)*dinv; acc[v] = hp[v] + sum_{s->v} hp[s];
//                  out[v] = dinv[v]*acc[v] + b.

constexpr int NT = 256;
constexpr int SCAN_E = 1024;   // elements per scan block (256 thr x 4)

// ---------------- histogram ----------------
__global__ void k_deg(const int* __restrict__ dst, int* __restrict__ deg, int E) {
    int e = blockIdx.x * blockDim.x + threadIdx.x;
    if (e < E) atomicAdd(deg + dst[e], 1);
}

// ---------------- 3-kernel exclusive scan of deg -> row ----------------
__global__ void k_scan1(const int* __restrict__ deg, int* __restrict__ row,
                        int* __restrict__ bsum, int N) {
    __shared__ int lds[NT];
    int base = blockIdx.x * SCAN_E + threadIdx.x * 4;
    int d0 = 0, d1 = 0, d2 = 0, d3 = 0;
    if (base + 3 < N) {
        int4 v = *(const int4*)(deg + base);
        d0 = v.x; d1 = v.y; d2 = v.z; d3 = v.w;
    } else {
        if (base     < N) d0 = deg[base];
        if (base + 1 < N) d1 = deg[base + 1];
        if (base + 2 < N) d2 = deg[base + 2];
        if (base + 3 < N) d3 = deg[base + 3];
    }
    int t = d0 + d1 + d2 + d3;
    lds[threadIdx.x] = t;
    __syncthreads();
    for (int off = 1; off < NT; off <<= 1) {
        int v = (threadIdx.x >= off) ? lds[threadIdx.x - off] : 0;
        __syncthreads();
        lds[threadIdx.x] += v;
        __syncthreads();
    }
    int excl = lds[threadIdx.x] - t;
    if (threadIdx.x == NT - 1) bsum[blockIdx.x] = lds[NT - 1];
    if (base     < N) row[base]     = excl;
    if (base + 1 < N) row[base + 1] = excl + d0;
    if (base + 2 < N) row[base + 2] = excl + d0 + d1;
    if (base + 3 < N) row[base + 3] = excl + d0 + d1 + d2;
}

__global__ void k_scan2(int* __restrict__ bsum, int M) {
    __shared__ int lds[NT];
    int base = threadIdx.x * 4;
    int d0 = 0, d1 = 0, d2 = 0, d3 = 0;
    if (base     < M) d0 = bsum[base];
    if (base + 1 < M) d1 = bsum[base + 1];
    if (base + 2 < M) d2 = bsum[base + 2];
    if (base + 3 < M) d3 = bsum[base + 3];
    int t = d0 + d1 + d2 + d3;
    lds[threadIdx.x] = t;
    __syncthreads();
    for (int off = 1; off < NT; off <<= 1) {
        int v = (threadIdx.x >= off) ? lds[threadIdx.x - off] : 0;
        __syncthreads();
        lds[threadIdx.x] += v;
        __syncthreads();
    }
    int excl = lds[threadIdx.x] - t;
    if (base     < M) bsum[base]     = excl;
    if (base + 1 < M) bsum[base + 1] = excl + d0;
    if (base + 2 < M) bsum[base + 2] = excl + d0 + d1;
    if (base + 3 < M) bsum[base + 3] = excl + d0 + d1 + d2;
}

__global__ void k_scan3(int* __restrict__ row, const int* __restrict__ bsum, int N) {
    int base = blockIdx.x * SCAN_E + threadIdx.x * 4;
    int add = bsum[blockIdx.x];
    if (base + 3 < N) {
        int4 v = *(int4*)(row + base);
        v.x += add; v.y += add; v.z += add; v.w += add;
        *(int4*)(row + base) = v;
    } else {
        if (base     < N) row[base]     += add;
        if (base + 1 < N) row[base + 1] += add;
        if (base + 2 < N) row[base + 2] += add;
    }
}

// ---------------- scatter: counting sort of src by dst ----------------
// After this, row[i] = end offset of node i (start = row[i-1], or 0).
__global__ void k_scatter(const int* __restrict__ src, const int* __restrict__ dst,
                          int* __restrict__ row, int* __restrict__ ss, int E) {
    int e = blockIdx.x * blockDim.x + threadIdx.x;
    if (e >= E) return;
    int s = src[e], d = dst[e];
    int slot = atomicAdd(row + d, 1);
    ss[slot] = s;
}

// ---------------- node transform 1: hp1 = (x@W1)*dinv ----------------
__global__ void k_node1(const float2* __restrict__ x, const int* __restrict__ deg,
                        const float* __restrict__ W1,
                        float* __restrict__ dinv, float4* __restrict__ hp, int N) {
    int i = blockIdx.x * blockDim.x + threadIdx.x;
    if (i >= N) return;
    float2 xi = x[i];
    float di = rsqrtf((float)(deg[i] + 1));
    dinv[i] = di;
    float4 h;
    h.x = (xi.x * W1[0] + xi.y * W1[4]) * di;
    h.y = (xi.x * W1[1] + xi.y * W1[5]) * di;
    h.z = (xi.x * W1[2] + xi.y * W1[6]) * di;
    h.w = (xi.x * W1[3] + xi.y * W1[7]) * di;
    hp[i] = h;
}

// ---------------- agg1 + node2 fused: hp2 = (relu(dinv*acc1+b1)@W2)*dinv ------
__global__ void k_aggf1(const int* __restrict__ row, const int* __restrict__ ss,
                        const float4* __restrict__ hp1, const float* __restrict__ dinv,
                        const float* __restrict__ b1, const float* __restrict__ W2,
                        float4* __restrict__ hp2, int N) {
    int i = blockIdx.x * blockDim.x + threadIdx.x;
    if (i >= N) return;
    int beg = (i == 0) ? 0 : row[i - 1];
    int end = row[i];
    float4 a = hp1[i];                       // self loop
    int e = beg;
    for (; e + 1 < end; e += 2) {
        float4 ha = hp1[ss[e]];
        float4 hb = hp1[ss[e + 1]];
        a.x += ha.x + hb.x; a.y += ha.y + hb.y;
        a.z += ha.z + hb.z; a.w += ha.w + hb.w;
    }
    if (e < end) {
        float4 ha = hp1[ss[e]];
        a.x += ha.x; a.y += ha.y; a.z += ha.z; a.w += ha.w;
    }
    float di = dinv[i];
    float o0 = fmaxf(di * a.x + b1[0], 0.f);
    float o1 = fmaxf(di * a.y + b1[1], 0.f);
    float o2 = fmaxf(di * a.z + b1[2], 0.f);
    float o3 = fmaxf(di * a.w + b1[3], 0.f);
    float4 h;
    h.x = (o0 * W2[0] + o1 * W2[3] + o2 * W2[6] + o3 * W2[9])  * di;
    h.y = (o0 * W2[1] + o1 * W2[4] + o2 * W2[7] + o3 * W2[10]) * di;
    h.z = (o0 * W2[2] + o1 * W2[5] + o2 * W2[8] + o3 * W2[11]) * di;
    h.w = 0.f;
    hp2[i] = h;
}

// ---------------- agg2 + node3 fused: sigmoid + MLP -> out ----------------
__global__ void k_aggf2(const int* __restrict__ row, const int* __restrict__ ss,
                        const float4* __restrict__ hp2, const float* __restrict__ dinv,
                        const float* __restrict__ b2,
                        const float* __restrict__ W3, const float* __restrict__ b3,
                        const float* __restrict__ W4, const float* __restrict__ b4,
                        const float* __restrict__ W5, const float* __restrict__ b5,
                        float* __restrict__ out, int N) {
    int i = blockIdx.x * blockDim.x + threadIdx.x;
    if (i >= N) return;
    int beg = (i == 0) ? 0 : row[i - 1];
    int end = row[i];
    float4 a = hp2[i];                       // self loop
    int e = beg;
    for (; e + 1 < end; e += 2) {
        float4 ha = hp2[ss[e]];
        float4 hb = hp2[ss[e + 1]];
        a.x += ha.x + hb.x; a.y += ha.y + hb.y; a.z += ha.z + hb.z;
    }
    if (e < end) {
        float4 ha = hp2[ss[e]];
        a.x += ha.x; a.y += ha.y; a.z += ha.z;
    }
    float di = dinv[i];
    float z0 = di * a.x + b2[0];
    float z1 = di * a.y + b2[1];
    float z2 = di * a.z + b2[2];
    float s0 = 1.f / (1.f + expf(-z0));
    float s1 = 1.f / (1.f + expf(-z1));
    float s2 = 1.f / (1.f + expf(-z2));
    float t0 = fmaxf(s0 * W3[0] + s1 * W3[4] + s2 * W3[8]  + b3[0], 0.f);
    float t1 = fmaxf(s0 * W3[1] + s1 * W3[5] + s2 * W3[9]  + b3[1], 0.f);
    float t2 = fmaxf(s0 * W3[2] + s1 * W3[6] + s2 * W3[10] + b3[2], 0.f);
    float t3 = fmaxf(s0 * W3[3] + s1 * W3[7] + s2 * W3[11] + b3[3], 0.f);
    float u0 = fmaxf(t0 * W4[0] + t1 * W4[3] + t2 * W4[6] + t3 * W4[9]  + b4[0], 0.f);
    float u1 = fmaxf(t0 * W4[1] + t1 * W4[4] + t2 * W4[7] + t3 * W4[10] + b4[1], 0.f);
    float u2 = fmaxf(t0 * W4[2] + t1 * W4[5] + t2 * W4[8] + t3 * W4[11] + b4[2], 0.f);
    out[i] = u0 * W5[0] + u1 * W5[1] + u2 * W5[2] + b5[0];
}

// ---------------- fallback (round-1 atomic path) ----------------
__global__ void k_node1_fb(const float2* __restrict__ x, const int* __restrict__ deg,
                           const float* __restrict__ W1,
                           float* __restrict__ dinv, float4* __restrict__ hp,
                           float4* __restrict__ acc, int N) {
    int i = blockIdx.x * blockDim.x + threadIdx.x;
    if (i >= N) return;
    float2 xi = x[i];
    float di = rsqrtf((float)(deg[i] + 1));
    dinv[i] = di;
    float4 h;
    h.x = (xi.x * W1[0] + xi.y * W1[4]) * di;
    h.y = (xi.x * W1[1] + xi.y * W1[5]) * di;
    h.z = (xi.x * W1[2] + xi.y * W1[6]) * di;
    h.w = (xi.x * W1[3] + xi.y * W1[7]) * di;
    hp[i] = h; acc[i] = h;
}
__global__ void k_agg4_fb(const int* __restrict__ src, const int* __restrict__ dst,
                          const float4* __restrict__ hp, float* __restrict__ acc, int E) {
    int e = blockIdx.x * blockDim.x + threadIdx.x;
    if (e >= E) return;
    int s = src[e], d = dst[e];
    float4 h = hp[s];
    float* p = acc + ((size_t)d << 2);
    unsafeAtomicAdd(p + 0, h.x); unsafeAtomicAdd(p + 1, h.y);
    unsafeAtomicAdd(p + 2, h.z); unsafeAtomicAdd(p + 3, h.w);
}
__global__ void k_node2_fb(const float* __restrict__ dinv, const float* __restrict__ b1,
                           const float* __restrict__ W2,
                           float4* __restrict__ bufA, float4* __restrict__ bufB, int N) {
    int i = blockIdx.x * blockDim.x + threadIdx.x;
    if (i >= N) return;
    float di = dinv[i];
    float4 a = bufB[i];
    float o0 = fmaxf(di * a.x + b1[0], 0.f);
    float o1 = fmaxf(di * a.y + b1[1], 0.f);
    float o2 = fmaxf(di * a.z + b1[2], 0.f);
    float o3 = fmaxf(di * a.w + b1[3], 0.f);
    float4 h;
    h.x = (o0 * W2[0] + o1 * W2[3] + o2 * W2[6] + o3 * W2[9])  * di;
    h.y = (o0 * W2[1] + o1 * W2[4] + o2 * W2[7] + o3 * W2[10]) * di;
    h.z = (o0 * W2[2] + o1 * W2[5] + o2 * W2[8] + o3 * W2[11]) * di;
    h.w = 0.f;
    bufA[i] = h; bufB[i] = h;
}
__global__ void k_agg3_fb(const int* __restrict__ src, const int* __restrict__ dst,
                          const float4* __restrict__ hp, float* __restrict__ acc, int E) {
    int e = blockIdx.x * blockDim.x + threadIdx.x;
    if (e >= E) return;
    int s = src[e], d = dst[e];
    float4 h = hp[s];
    float* p = acc + ((size_t)d << 2);
    unsafeAtomicAdd(p + 0, h.x); unsafeAtomicAdd(p + 1, h.y); unsafeAtomicAdd(p + 2, h.z);
}
__global__ void k_node3_fb(const float* __restrict__ dinv, const float4* __restrict__ acc,
                           const float* __restrict__ b2,
                           const float* __restrict__ W3, const float* __restrict__ b3,
                           const float* __restrict__ W4, const float* __restrict__ b4,
                           const float* __restrict__ W5, const float* __restrict__ b5,
                           float* __restrict__ out, int N) {
    int i = blockIdx.x * blockDim.x + threadIdx.x;
    if (i >= N) return;
    float di = dinv[i];
    float4 a = acc[i];
    float z0 = di * a.x + b2[0];
    float z1 = di * a.y + b2[1];
    float z2 = di * a.z + b2[2];
    float s0 = 1.f / (1.f + expf(-z0));
    float s1 = 1.f / (1.f + expf(-z1));
    float s2 = 1.f / (1.f + expf(-z2));
    float t0 = fmaxf(s0 * W3[0] + s1 * W3[4] + s2 * W3[8]  + b3[0], 0.f);
    float t1 = fmaxf(s0 * W3[1] + s1 * W3[5] + s2 * W3[9]  + b3[1], 0.f);
    float t2 = fmaxf(s0 * W3[2] + s1 * W3[6] + s2 * W3[10] + b3[2], 0.f);
    float t3 = fmaxf(s0 * W3[3] + s1 * W3[7] + s2 * W3[11] + b3[3], 0.f);
    float u0 = fmaxf(t0 * W4[0] + t1 * W4[3] + t2 * W4[6] + t3 * W4[9]  + b4[0], 0.f);
    float u1 = fmaxf(t0 * W4[1] + t1 * W4[4] + t2 * W4[7] + t3 * W4[10] + b4[1], 0.f);
    float u2 = fmaxf(t0 * W4[2] + t1 * W4[5] + t2 * W4[8] + t3 * W4[11] + b4[2], 0.f);
    out[i] = u0 * W5[0] + u1 * W5[1] + u2 * W5[2] + b5[0];
}

extern "C" void kernel_launch(void* const* d_in, const int* in_sizes, int n_in,
                              void* d_out, int out_size, void* d_ws, size_t ws_size,
                              hipStream_t stream) {
    const float* x  = (const float*)d_in[0];
    const int*   ei = (const int*)d_in[1];
    const float* W1 = (const float*)d_in[2];
    const float* b1 = (const float*)d_in[3];
    const float* W2 = (const float*)d_in[4];
    const float* b2 = (const float*)d_in[5];
    const float* W3 = (const float*)d_in[6];
    const float* b3 = (const float*)d_in[7];
    const float* W4 = (const float*)d_in[8];
    const float* b4 = (const float*)d_in[9];
    const float* W5 = (const float*)d_in[10];
    const float* b5 = (const float*)d_in[11];

    const int N = in_sizes[0] / 2;
    const int E = in_sizes[1] / 2;
    const int* src = ei;
    const int* dst = ei + E;

    const int gbE = (E + NT - 1) / NT;
    const int gbN = (N + NT - 1) / NT;
    const int nScanBlocks = (N + SCAN_E - 1) / SCAN_E;   // 977 for N=1M (<= 1024)

    char* ws = (char*)d_ws;
    const size_t need = (size_t)N * 44 + (size_t)E * 4 + (size_t)nScanBlocks * 4 + 256;

    if (ws_size >= need && nScanBlocks <= NT * 4) {
        float4* hp1  = (float4*)ws;                                   // 16N
        float4* hp2  = (float4*)(ws + (size_t)N * 16);                // 16N
        int*    ss   = (int*)   (ws + (size_t)N * 32);                // 4E
        int*    deg  = (int*)   (ws + (size_t)N * 32 + (size_t)E * 4);// 4N
        int*    row  = (int*)   (ws + (size_t)N * 36 + (size_t)E * 4);// 4N
        float*  dinv = (float*) (ws + (size_t)N * 40 + (size_t)E * 4);// 4N
        int*    bsum = (int*)   (ws + (size_t)N * 44 + (size_t)E * 4);// 4*nScanBlocks

        hipMemsetAsync(deg, 0, (size_t)N * 4, stream);
        k_deg   <<<gbE, NT, 0, stream>>>(dst, deg, E);
        k_scan1 <<<nScanBlocks, NT, 0, stream>>>(deg, row, bsum, N);
        k_scan2 <<<1, NT, 0, stream>>>(bsum, nScanBlocks);
        k_scan3 <<<nScanBlocks, NT, 0, stream>>>(row, bsum, N);
        k_node1 <<<gbN, NT, 0, stream>>>((const float2*)x, deg, W1, dinv, hp1, N);
        k_scatter<<<gbE, NT, 0, stream>>>(src, dst, row, ss, E);
        k_aggf1 <<<gbN, NT, 0, stream>>>(row, ss, hp1, dinv, b1, W2, hp2, N);
        k_aggf2 <<<gbN, NT, 0, stream>>>(row, ss, hp2, dinv, b2, W3, b3, W4, b4,
                                         W5, b5, (float*)d_out, N);
    } else {
        int*    deg  = (int*)ws;
        float*  dinv = (float*)(ws + (size_t)N * 4);
        float4* bufA = (float4*)(ws + (size_t)N * 8);
        float4* bufB = (float4*)(ws + (size_t)N * 8 + (size_t)N * 16);

        hipMemsetAsync(deg, 0, (size_t)N * 4, stream);
        k_deg     <<<gbE, NT, 0, stream>>>(dst, deg, E);
        k_node1_fb<<<gbN, NT, 0, stream>>>((const float2*)x, deg, W1, dinv, bufA, bufB, N);
        k_agg4_fb <<<gbE, NT, 0, stream>>>(src, dst, bufA, (float*)bufB, E);
        k_node2_fb<<<gbN, NT, 0, stream>>>(dinv, b1, W2, bufA, bufB, N);
        k_agg3_fb <<<gbE, NT, 0, stream>>>(src, dst, bufA, (float*)bufB, E);
        k_node3_fb<<<gbN, NT, 0, stream>>>(dinv, bufB, b2, W3, b3, W4, b4, W5, b5,
                                           (float*)d_out, N);
    }
}

// Round 4
// 1263.342 us; speedup vs baseline: 4.9461x; 1.8853x over previous
//
#include <hip/hip_runtime.h>
#include <hip/hip_bf16.h>

// GCN via two-level bucketed counting-sort CSR (no global float atomics,
// no global 4B random scatter):
//  passA: bin edges by dst>>11 into 489 buckets, payload packed to 4B
//         (src | dst_low<<20), LDS-staged coalesced-ish writes.
//  passB: one block per bucket: LDS count + LDS scan -> deg/row/ss, all
//         ss writes land in a 64KB L2-resident region.
//  Then gather-only aggregation with fused epilogues.

constexpr int NT = 256;
constexpr int SCAN_E = 1024;   // fallback scan tile
constexpr int B2 = 11;
constexpr int BN = 1 << B2;    // 2048 nodes / bucket
constexpr int NBMAX = 512;
constexpr int TILE = 4096;     // edges per passA tile

// ================= pass A: bucket histogram =================
__global__ void k_binhist(const int* __restrict__ dst, int* __restrict__ ghist, int E) {
    __shared__ int cnt[NBMAX];
    int t0 = blockIdx.x * TILE;
    for (int l = threadIdx.x; l < NBMAX; l += NT) cnt[l] = 0;
    __syncthreads();
    for (int k = 0; k < TILE / (NT * 4); ++k) {
        int idx = t0 + (k * NT + threadIdx.x) * 4;
        if (idx + 3 < E) {
            int4 d4 = *(const int4*)(dst + idx);
            atomicAdd(&cnt[d4.x >> B2], 1);
            atomicAdd(&cnt[d4.y >> B2], 1);
            atomicAdd(&cnt[d4.z >> B2], 1);
            atomicAdd(&cnt[d4.w >> B2], 1);
        } else {
            for (int j = 0; j < 4; ++j)
                if (idx + j < E) atomicAdd(&cnt[dst[idx + j] >> B2], 1);
        }
    }
    __syncthreads();
    for (int l = threadIdx.x; l < NBMAX; l += NT)
        if (cnt[l]) atomicAdd(&ghist[l], cnt[l]);
}

// ================= scan buckets (1 block of NBMAX thr) =================
__global__ void k_scanbuckets(const int* __restrict__ ghist, int* __restrict__ gbase,
                              int* __restrict__ gcur, int NB, int E) {
    __shared__ int part[NBMAX];
    int tid = threadIdx.x;
    int t = (tid < NB) ? ghist[tid] : 0;
    part[tid] = t;
    __syncthreads();
    for (int off = 1; off < NBMAX; off <<= 1) {
        int v = (tid >= off) ? part[tid - off] : 0;
        __syncthreads();
        part[tid] += v;
        __syncthreads();
    }
    int excl = part[tid] - t;
    if (tid < NB) { gbase[tid] = excl; gcur[tid] = excl; }
    if (tid == 0) gbase[NB] = E;
}

// ========== pass A scatter: bin packed (src | dlow<<20) by dst>>B2 ==========
__global__ void k_binscatter(const int* __restrict__ src, const int* __restrict__ dst,
                             int* __restrict__ gcur, int* __restrict__ pairs,
                             int E, int NB) {
    __shared__ int cnt[NBMAX], lbase[NBMAX], cur[NBMAX], gpos[NBMAX];
    __shared__ int part[NT];
    __shared__ int lbuf[TILE];
    int t0 = blockIdx.x * TILE;
    int tid = threadIdx.x;
    for (int l = tid; l < NBMAX; l += NT) cnt[l] = 0;
    __syncthreads();
    // count
    for (int k = 0; k < TILE / (NT * 4); ++k) {
        int idx = t0 + (k * NT + tid) * 4;
        if (idx + 3 < E) {
            int4 d4 = *(const int4*)(dst + idx);
            atomicAdd(&cnt[d4.x >> B2], 1);
            atomicAdd(&cnt[d4.y >> B2], 1);
            atomicAdd(&cnt[d4.z >> B2], 1);
            atomicAdd(&cnt[d4.w >> B2], 1);
        } else {
            for (int j = 0; j < 4; ++j)
                if (idx + j < E) atomicAdd(&cnt[dst[idx + j] >> B2], 1);
        }
    }
    __syncthreads();
    // scan 512 counters with 256 threads (chunk of 2)
    int c0 = cnt[2 * tid], c1 = cnt[2 * tid + 1];
    int t = c0 + c1;
    part[tid] = t;
    __syncthreads();
    for (int off = 1; off < NT; off <<= 1) {
        int v = (tid >= off) ? part[tid - off] : 0;
        __syncthreads();
        part[tid] += v;
        __syncthreads();
    }
    int ex = part[tid] - t;
    lbase[2 * tid] = ex;          cur[2 * tid] = ex;
    lbase[2 * tid + 1] = ex + c0; cur[2 * tid + 1] = ex + c0;
    __syncthreads();
    // reserve global ranges
    for (int j = tid; j < NBMAX; j += NT)
        if (j < NB && cnt[j]) gpos[j] = atomicAdd(&gcur[j], cnt[j]);
    __syncthreads();
    // place into LDS sorted by bucket
    for (int k = 0; k < TILE / (NT * 4); ++k) {
        int idx = t0 + (k * NT + tid) * 4;
        if (idx + 3 < E) {
            int4 s4 = *(const int4*)(src + idx);
            int4 d4 = *(const int4*)(dst + idx);
            int b, sl;
            b = d4.x >> B2; sl = atomicAdd(&cur[b], 1);
            lbuf[sl] = s4.x | ((d4.x & (BN - 1)) << 20);
            b = d4.y >> B2; sl = atomicAdd(&cur[b], 1);
            lbuf[sl] = s4.y | ((d4.y & (BN - 1)) << 20);
            b = d4.z >> B2; sl = atomicAdd(&cur[b], 1);
            lbuf[sl] = s4.z | ((d4.z & (BN - 1)) << 20);
            b = d4.w >> B2; sl = atomicAdd(&cur[b], 1);
            lbuf[sl] = s4.w | ((d4.w & (BN - 1)) << 20);
        } else {
            for (int j = 0; j < 4; ++j) {
                if (idx + j < E) {
                    int s = src[idx + j], d = dst[idx + j];
                    int b = d >> B2;
                    int sl = atomicAdd(&cur[b], 1);
                    lbuf[sl] = s | ((d & (BN - 1)) << 20);
                }
            }
        }
    }
    __syncthreads();
    // copy out: thread j handles buckets j, j+NT (contiguous runs)
    for (int j = tid; j < NBMAX; j += NT) {
        if (j >= NB) continue;
        int n = cnt[j];
        if (!n) continue;
        int gd = gpos[j], lb = lbase[j];
        for (int i2 = 0; i2 < n; ++i2) pairs[gd + i2] = lbuf[lb + i2];
    }
}

// ========== pass B: per-bucket CSR build (one block / bucket) ==========
__global__ void __launch_bounds__(512)
k_buildcsr(const int* __restrict__ pairs, const int* __restrict__ gbase,
           int* __restrict__ ss, int* __restrict__ deg, int* __restrict__ row, int N) {
    __shared__ int cnt[BN];
    __shared__ int pos[BN];
    __shared__ int part[512];
    int b = blockIdx.x, tid = threadIdx.x;
    int eBeg = gbase[b], eEnd = gbase[b + 1];
    int nodeBase = b << B2;
    for (int l = tid; l < BN; l += 512) cnt[l] = 0;
    __syncthreads();
    for (int e = eBeg + tid; e < eEnd; e += 512)
        atomicAdd(&cnt[((unsigned)pairs[e]) >> 20], 1);
    __syncthreads();
    int l0 = tid * 4;                       // BN/512 == 4
    int c0 = cnt[l0], c1 = cnt[l0 + 1], c2 = cnt[l0 + 2], c3 = cnt[l0 + 3];
    int g = nodeBase + l0;
    if (g + 3 < N) *(int4*)(deg + g) = make_int4(c0, c1, c2, c3);
    else {
        if (g < N) deg[g] = c0;
        if (g + 1 < N) deg[g + 1] = c1;
        if (g + 2 < N) deg[g + 2] = c2;
        if (g + 3 < N) deg[g + 3] = c3;
    }
    int t = c0 + c1 + c2 + c3;
    part[tid] = t;
    __syncthreads();
    for (int off = 1; off < 512; off <<= 1) {
        int v = (tid >= off) ? part[tid - off] : 0;
        __syncthreads();
        part[tid] += v;
        __syncthreads();
    }
    int ex = part[tid] - t;
    pos[l0]     = eBeg + ex;
    pos[l0 + 1] = eBeg + ex + c0;
    pos[l0 + 2] = eBeg + ex + c0 + c1;
    pos[l0 + 3] = eBeg + ex + c0 + c1 + c2;
    int r0 = eBeg + ex + c0, r1 = r0 + c1, r2 = r1 + c2, r3 = r2 + c3;
    if (g + 3 < N) *(int4*)(row + g) = make_int4(r0, r1, r2, r3);
    else {
        if (g < N) row[g] = r0;
        if (g + 1 < N) row[g + 1] = r1;
        if (g + 2 < N) row[g + 2] = r2;
        if (g + 3 < N) row[g + 3] = r3;
    }
    __syncthreads();
    for (int e = eBeg + tid; e < eEnd; e += 512) {
        unsigned v = (unsigned)pairs[e];
        int sl = atomicAdd(&pos[v >> 20], 1);
        ss[sl] = (int)(v & 0xFFFFFu);
    }
}

// ================= node transform 1: hp1 = (x@W1)*dinv =================
__global__ void k_node1(const float2* __restrict__ x, const int* __restrict__ deg,
                        const float* __restrict__ W1,
                        float* __restrict__ dinv, float4* __restrict__ hp, int N) {
    int i = blockIdx.x * blockDim.x + threadIdx.x;
    if (i >= N) return;
    float2 xi = x[i];
    float di = rsqrtf((float)(deg[i] + 1));
    dinv[i] = di;
    float4 h;
    h.x = (xi.x * W1[0] + xi.y * W1[4]) * di;
    h.y = (xi.x * W1[1] + xi.y * W1[5]) * di;
    h.z = (xi.x * W1[2] + xi.y * W1[6]) * di;
    h.w = (xi.x * W1[3] + xi.y * W1[7]) * di;
    hp[i] = h;
}

// ========== agg1 + node2 fused ==========
__global__ void k_aggf1(const int* __restrict__ row, const int* __restrict__ ss,
                        const float4* __restrict__ hp1, const float* __restrict__ dinv,
                        const float* __restrict__ b1, const float* __restrict__ W2,
                        float4* __restrict__ hp2, int N) {
    int i = blockIdx.x * blockDim.x + threadIdx.x;
    if (i >= N) return;
    int beg = (i == 0) ? 0 : row[i - 1];
    int end = row[i];
    float4 a = hp1[i];
    int e = beg;
    for (; e + 1 < end; e += 2) {
        float4 ha = hp1[ss[e]];
        float4 hb = hp1[ss[e + 1]];
        a.x += ha.x + hb.x; a.y += ha.y + hb.y;
        a.z += ha.z + hb.z; a.w += ha.w + hb.w;
    }
    if (e < end) {
        float4 ha = hp1[ss[e]];
        a.x += ha.x; a.y += ha.y; a.z += ha.z; a.w += ha.w;
    }
    float di = dinv[i];
    float o0 = fmaxf(di * a.x + b1[0], 0.f);
    float o1 = fmaxf(di * a.y + b1[1], 0.f);
    float o2 = fmaxf(di * a.z + b1[2], 0.f);
    float o3 = fmaxf(di * a.w + b1[3], 0.f);
    float4 h;
    h.x = (o0 * W2[0] + o1 * W2[3] + o2 * W2[6] + o3 * W2[9])  * di;
    h.y = (o0 * W2[1] + o1 * W2[4] + o2 * W2[7] + o3 * W2[10]) * di;
    h.z = (o0 * W2[2] + o1 * W2[5] + o2 * W2[8] + o3 * W2[11]) * di;
    h.w = 0.f;
    hp2[i] = h;
}

// ========== agg2 + node3 fused (sigmoid + MLP head) ==========
__global__ void k_aggf2(const int* __restrict__ row, const int* __restrict__ ss,
                        const float4* __restrict__ hp2, const float* __restrict__ dinv,
                        const float* __restrict__ b2,
                        const float* __restrict__ W3, const float* __restrict__ b3,
                        const float* __restrict__ W4, const float* __restrict__ b4,
                        const float* __restrict__ W5, const float* __restrict__ b5,
                        float* __restrict__ out, int N) {
    int i = blockIdx.x * blockDim.x + threadIdx.x;
    if (i >= N) return;
    int beg = (i == 0) ? 0 : row[i - 1];
    int end = row[i];
    float4 a = hp2[i];
    int e = beg;
    for (; e + 1 < end; e += 2) {
        float4 ha = hp2[ss[e]];
        float4 hb = hp2[ss[e + 1]];
        a.x += ha.x + hb.x; a.y += ha.y + hb.y; a.z += ha.z + hb.z;
    }
    if (e < end) {
        float4 ha = hp2[ss[e]];
        a.x += ha.x; a.y += ha.y; a.z += ha.z;
    }
    float di = dinv[i];
    float z0 = di * a.x + b2[0];
    float z1 = di * a.y + b2[1];
    float z2 = di * a.z + b2[2];
    float s0 = 1.f / (1.f + expf(-z0));
    float s1 = 1.f / (1.f + expf(-z1));
    float s2 = 1.f / (1.f + expf(-z2));
    float t0 = fmaxf(s0 * W3[0] + s1 * W3[4] + s2 * W3[8]  + b3[0], 0.f);
    float t1 = fmaxf(s0 * W3[1] + s1 * W3[5] + s2 * W3[9]  + b3[1], 0.f);
    float t2 = fmaxf(s0 * W3[2] + s1 * W3[6] + s2 * W3[10] + b3[2], 0.f);
    float t3 = fmaxf(s0 * W3[3] + s1 * W3[7] + s2 * W3[11] + b3[3], 0.f);
    float u0 = fmaxf(t0 * W4[0] + t1 * W4[3] + t2 * W4[6] + t3 * W4[9]  + b4[0], 0.f);
    float u1 = fmaxf(t0 * W4[1] + t1 * W4[4] + t2 * W4[7] + t3 * W4[10] + b4[1], 0.f);
    float u2 = fmaxf(t0 * W4[2] + t1 * W4[5] + t2 * W4[8] + t3 * W4[11] + b4[2], 0.f);
    out[i] = u0 * W5[0] + u1 * W5[1] + u2 * W5[2] + b5[0];
}

// ================= fallback path (round-2 CSR) =================
__global__ void k_deg(const int* __restrict__ dst, int* __restrict__ deg, int E) {
    int e = blockIdx.x * blockDim.x + threadIdx.x;
    if (e < E) atomicAdd(deg + dst[e], 1);
}
__global__ void k_scan1(const int* __restrict__ deg, int* __restrict__ row,
                        int* __restrict__ bsum, int N) {
    __shared__ int lds[NT];
    int base = blockIdx.x * SCAN_E + threadIdx.x * 4;
    int d0 = 0, d1 = 0, d2 = 0, d3 = 0;
    if (base + 3 < N) {
        int4 v = *(const int4*)(deg + base);
        d0 = v.x; d1 = v.y; d2 = v.z; d3 = v.w;
    } else {
        if (base     < N) d0 = deg[base];
        if (base + 1 < N) d1 = deg[base + 1];
        if (base + 2 < N) d2 = deg[base + 2];
        if (base + 3 < N) d3 = deg[base + 3];
    }
    int t = d0 + d1 + d2 + d3;
    lds[threadIdx.x] = t;
    __syncthreads();
    for (int off = 1; off < NT; off <<= 1) {
        int v = (threadIdx.x >= off) ? lds[threadIdx.x - off] : 0;
        __syncthreads();
        lds[threadIdx.x] += v;
        __syncthreads();
    }
    int excl = lds[threadIdx.x] - t;
    if (threadIdx.x == NT - 1) bsum[blockIdx.x] = lds[NT - 1];
    if (base     < N) row[base]     = excl;
    if (base + 1 < N) row[base + 1] = excl + d0;
    if (base + 2 < N) row[base + 2] = excl + d0 + d1;
    if (base + 3 < N) row[base + 3] = excl + d0 + d1 + d2;
}
__global__ void k_scan2(int* __restrict__ bsum, int M) {
    __shared__ int lds[NT];
    int base = threadIdx.x * 4;
    int d0 = 0, d1 = 0, d2 = 0, d3 = 0;
    if (base     < M) d0 = bsum[base];
    if (base + 1 < M) d1 = bsum[base + 1];
    if (base + 2 < M) d2 = bsum[base + 2];
    if (base + 3 < M) d3 = bsum[base + 3];
    int t = d0 + d1 + d2 + d3;
    lds[threadIdx.x] = t;
    __syncthreads();
    for (int off = 1; off < NT; off <<= 1) {
        int v = (threadIdx.x >= off) ? lds[threadIdx.x - off] : 0;
        __syncthreads();
        lds[threadIdx.x] += v;
        __syncthreads();
    }
    int excl = lds[threadIdx.x] - t;
    if (base     < M) bsum[base]     = excl;
    if (base + 1 < M) bsum[base + 1] = excl + d0;
    if (base + 2 < M) bsum[base + 2] = excl + d0 + d1;
    if (base + 3 < M) bsum[base + 3] = excl + d0 + d1 + d2;
}
__global__ void k_scan3(int* __restrict__ row, const int* __restrict__ bsum, int N) {
    int base = blockIdx.x * SCAN_E + threadIdx.x * 4;
    int add = bsum[blockIdx.x];
    if (base + 3 < N) {
        int4 v = *(int4*)(row + base);
        v.x += add; v.y += add; v.z += add; v.w += add;
        *(int4*)(row + base) = v;
    } else {
        if (base     < N) row[base]     += add;
        if (base + 1 < N) row[base + 1] += add;
        if (base + 2 < N) row[base + 2] += add;
    }
}
__global__ void k_scatter(const int* __restrict__ src, const int* __restrict__ dst,
                          int* __restrict__ row, int* __restrict__ ss, int E) {
    int e = blockIdx.x * blockDim.x + threadIdx.x;
    if (e >= E) return;
    int s = src[e], d = dst[e];
    int slot = atomicAdd(row + d, 1);
    ss[slot] = s;
}

extern "C" void kernel_launch(void* const* d_in, const int* in_sizes, int n_in,
                              void* d_out, int out_size, void* d_ws, size_t ws_size,
                              hipStream_t stream) {
    const float* x  = (const float*)d_in[0];
    const int*   ei = (const int*)d_in[1];
    const float* W1 = (const float*)d_in[2];
    const float* b1 = (const float*)d_in[3];
    const float* W2 = (const float*)d_in[4];
    const float* b2 = (const float*)d_in[5];
    const float* W3 = (const float*)d_in[6];
    const float* b3 = (const float*)d_in[7];
    const float* W4 = (const float*)d_in[8];
    const float* b4 = (const float*)d_in[9];
    const float* W5 = (const float*)d_in[10];
    const float* b5 = (const float*)d_in[11];

    const int N = in_sizes[0] / 2;
    const int E = in_sizes[1] / 2;
    const int* src = ei;
    const int* dst = ei + E;

    const int gbN = (N + NT - 1) / NT;
    const int gbE = (E + NT - 1) / NT;
    const int tiles = (E + TILE - 1) / TILE;
    const int NB = (N + BN - 1) >> B2;

    char* ws = (char*)d_ws;

    // -------- primary: two-level bucketed CSR --------
    size_t R0 = (size_t)E * 4;
    if (R0 < (size_t)N * 36) R0 = (size_t)N * 36;       // pairs overlays hp1/hp2/dinv
    size_t need1 = R0 + (size_t)E * 4 + (size_t)N * 8 + 3 * (NBMAX + 1) * 4 + 256;

    if (N <= (1 << 20) && NB <= NBMAX && ws_size >= need1) {
        int*    pairs = (int*)ws;                                   // [R0) pass A->B
        float4* hp1   = (float4*)ws;                                // reuse after passB
        float4* hp2   = (float4*)(ws + (size_t)N * 16);
        float*  dinv  = (float*) (ws + (size_t)N * 32);
        int*    ss    = (int*)(ws + R0);                            // E*4
        int*    deg   = (int*)(ws + R0 + (size_t)E * 4);            // N*4
        int*    row   = (int*)(ws + R0 + (size_t)E * 4 + (size_t)N * 4); // N*4
        int*    ghist = (int*)(ws + R0 + (size_t)E * 4 + (size_t)N * 8);
        int*    gbase = ghist + (NBMAX + 1);
        int*    gcur  = gbase + (NBMAX + 1);

        hipMemsetAsync(ghist, 0, (NBMAX + 1) * 4, stream);
        k_binhist    <<<tiles, NT, 0, stream>>>(dst, ghist, E);
        k_scanbuckets<<<1, NBMAX, 0, stream>>>(ghist, gbase, gcur, NB, E);
        k_binscatter <<<tiles, NT, 0, stream>>>(src, dst, gcur, pairs, E, NB);
        k_buildcsr   <<<NB, 512, 0, stream>>>(pairs, gbase, ss, deg, row, N);
        k_node1      <<<gbN, NT, 0, stream>>>((const float2*)x, deg, W1, dinv, hp1, N);
        k_aggf1      <<<gbN, NT, 0, stream>>>(row, ss, hp1, dinv, b1, W2, hp2, N);
        k_aggf2      <<<gbN, NT, 0, stream>>>(row, ss, hp2, dinv, b2, W3, b3, W4, b4,
                                              W5, b5, (float*)d_out, N);
        return;
    }

    // -------- fallback: round-2 global counting-sort CSR --------
    const int nScanBlocks = (N + SCAN_E - 1) / SCAN_E;
    size_t need2 = (size_t)N * 44 + (size_t)E * 4 + (size_t)nScanBlocks * 4 + 256;
    if (ws_size >= need2 && nScanBlocks <= NT * 4) {
        float4* hp1  = (float4*)ws;
        float4* hp2  = (float4*)(ws + (size_t)N * 16);
        int*    ss   = (int*)   (ws + (size_t)N * 32);
        int*    deg  = (int*)   (ws + (size_t)N * 32 + (size_t)E * 4);
        int*    row  = (int*)   (ws + (size_t)N * 36 + (size_t)E * 4);
        float*  dinv = (float*) (ws + (size_t)N * 40 + (size_t)E * 4);
        int*    bsum = (int*)   (ws + (size_t)N * 44 + (size_t)E * 4);

        hipMemsetAsync(deg, 0, (size_t)N * 4, stream);
        k_deg    <<<gbE, NT, 0, stream>>>(dst, deg, E);
        k_scan1  <<<nScanBlocks, NT, 0, stream>>>(deg, row, bsum, N);
        k_scan2  <<<1, NT, 0, stream>>>(bsum, nScanBlocks);
        k_scan3  <<<nScanBlocks, NT, 0, stream>>>(row, bsum, N);
        k_node1  <<<gbN, NT, 0, stream>>>((const float2*)x, deg, W1, dinv, hp1, N);
        k_scatter<<<gbE, NT, 0, stream>>>(src, dst, row, ss, E);
        k_aggf1  <<<gbN, NT, 0, stream>>>(row, ss, hp1, dinv, b1, W2, hp2, N);
        k_aggf2  <<<gbN, NT, 0, stream>>>(row, ss, hp2, dinv, b2, W3, b3, W4, b4,
                                          W5, b5, (float*)d_out, N);
    }
}

// Round 5
// 1122.239 us; speedup vs baseline: 5.5680x; 1.1257x over previous
//
#include <hip/hip_runtime.h>
#include <hip/hip_bf16.h>
#include <hip/hip_fp16.h>

// GCN, bucketed counting-sort CSR + L2-resident fp16 gather arrays.
//  Layer1 trick: (x@W1)*dinv == (x*dinv)@W1  -> aggregate y = x*dinv (2ch, half2,
//  4MB: fits per-XCD L2) and apply W1 post-aggregation.
//  Layer2: gather hp2 = (X1@W2)*dinv stored as half4 (8MB) for gathers; fp32 copy
//  kept for the self-loop term. All accumulation in fp32.

constexpr int NT = 256;
constexpr int SCAN_E = 1024;   // fallback scan tile
constexpr int B2 = 11;
constexpr int BN = 1 << B2;    // 2048 nodes / bucket
constexpr int NBMAX = 512;
constexpr int TILE = 4096;     // edges per passA tile

// ================= pass A: bucket histogram =================
__global__ void k_binhist(const int* __restrict__ dst, int* __restrict__ ghist, int E) {
    __shared__ int cnt[NBMAX];
    int t0 = blockIdx.x * TILE;
    for (int l = threadIdx.x; l < NBMAX; l += NT) cnt[l] = 0;
    __syncthreads();
    for (int k = 0; k < TILE / (NT * 4); ++k) {
        int idx = t0 + (k * NT + threadIdx.x) * 4;
        if (idx + 3 < E) {
            int4 d4 = *(const int4*)(dst + idx);
            atomicAdd(&cnt[d4.x >> B2], 1);
            atomicAdd(&cnt[d4.y >> B2], 1);
            atomicAdd(&cnt[d4.z >> B2], 1);
            atomicAdd(&cnt[d4.w >> B2], 1);
        } else {
            for (int j = 0; j < 4; ++j)
                if (idx + j < E) atomicAdd(&cnt[dst[idx + j] >> B2], 1);
        }
    }
    __syncthreads();
    for (int l = threadIdx.x; l < NBMAX; l += NT)
        if (cnt[l]) atomicAdd(&ghist[l], cnt[l]);
}

// ================= scan buckets =================
__global__ void k_scanbuckets(const int* __restrict__ ghist, int* __restrict__ gbase,
                              int* __restrict__ gcur, int NB, int E) {
    __shared__ int part[NBMAX];
    int tid = threadIdx.x;
    int t = (tid < NB) ? ghist[tid] : 0;
    part[tid] = t;
    __syncthreads();
    for (int off = 1; off < NBMAX; off <<= 1) {
        int v = (tid >= off) ? part[tid - off] : 0;
        __syncthreads();
        part[tid] += v;
        __syncthreads();
    }
    int excl = part[tid] - t;
    if (tid < NB) { gbase[tid] = excl; gcur[tid] = excl; }
    if (tid == 0) gbase[NB] = E;
}

// ========== pass A scatter: bin packed (src | dlow<<20) by dst>>B2 ==========
__global__ void k_binscatter(const int* __restrict__ src, const int* __restrict__ dst,
                             int* __restrict__ gcur, int* __restrict__ pairs,
                             int E, int NB) {
    __shared__ int cnt[NBMAX], cur[NBMAX], gpos[NBMAX];
    __shared__ int lbase2[NBMAX + 1];
    __shared__ int part[NT];
    __shared__ int lbuf[TILE];
    __shared__ int totalSh;
    int t0 = blockIdx.x * TILE;
    int tid = threadIdx.x;
    for (int l = tid; l < NBMAX; l += NT) cnt[l] = 0;
    __syncthreads();
    // count
    for (int k = 0; k < TILE / (NT * 4); ++k) {
        int idx = t0 + (k * NT + tid) * 4;
        if (idx + 3 < E) {
            int4 d4 = *(const int4*)(dst + idx);
            atomicAdd(&cnt[d4.x >> B2], 1);
            atomicAdd(&cnt[d4.y >> B2], 1);
            atomicAdd(&cnt[d4.z >> B2], 1);
            atomicAdd(&cnt[d4.w >> B2], 1);
        } else {
            for (int j = 0; j < 4; ++j)
                if (idx + j < E) atomicAdd(&cnt[dst[idx + j] >> B2], 1);
        }
    }
    __syncthreads();
    // scan 512 counters with 256 threads (chunk of 2)
    int c0 = cnt[2 * tid], c1 = cnt[2 * tid + 1];
    int t = c0 + c1;
    part[tid] = t;
    __syncthreads();
    for (int off = 1; off < NT; off <<= 1) {
        int v = (tid >= off) ? part[tid - off] : 0;
        __syncthreads();
        part[tid] += v;
        __syncthreads();
    }
    int ex = part[tid] - t;
    lbase2[2 * tid] = ex;          cur[2 * tid] = ex;
    lbase2[2 * tid + 1] = ex + c0; cur[2 * tid + 1] = ex + c0;
    if (tid == NT - 1) { lbase2[NBMAX] = part[NT - 1]; totalSh = part[NT - 1]; }
    __syncthreads();
    // reserve global ranges
    for (int j = tid; j < NBMAX; j += NT)
        if (j < NB && cnt[j]) gpos[j] = atomicAdd(&gcur[j], cnt[j]);
    __syncthreads();
    // place into LDS sorted by bucket
    for (int k = 0; k < TILE / (NT * 4); ++k) {
        int idx = t0 + (k * NT + tid) * 4;
        if (idx + 3 < E) {
            int4 s4 = *(const int4*)(src + idx);
            int4 d4 = *(const int4*)(dst + idx);
            int b, sl;
            b = d4.x >> B2; sl = atomicAdd(&cur[b], 1);
            lbuf[sl] = s4.x | ((d4.x & (BN - 1)) << 20);
            b = d4.y >> B2; sl = atomicAdd(&cur[b], 1);
            lbuf[sl] = s4.y | ((d4.y & (BN - 1)) << 20);
            b = d4.z >> B2; sl = atomicAdd(&cur[b], 1);
            lbuf[sl] = s4.z | ((d4.z & (BN - 1)) << 20);
            b = d4.w >> B2; sl = atomicAdd(&cur[b], 1);
            lbuf[sl] = s4.w | ((d4.w & (BN - 1)) << 20);
        } else {
            for (int j = 0; j < 4; ++j) {
                if (idx + j < E) {
                    int s = src[idx + j], d = dst[idx + j];
                    int b = d >> B2;
                    int sl = atomicAdd(&cur[b], 1);
                    lbuf[sl] = s | ((d & (BN - 1)) << 20);
                }
            }
        }
    }
    __syncthreads();
    // coalesced copy-out: consecutive tids -> consecutive global addrs.
    // bucket(idx) via binary search in lbase2 (largest j with lbase2[j] <= idx).
    int total = totalSh;
    for (int idx = tid; idx < total; idx += NT) {
        int lo = 0, hi = NBMAX - 1;
        while (lo < hi) {
            int mid = (lo + hi + 1) >> 1;
            if (lbase2[mid] <= idx) lo = mid; else hi = mid - 1;
        }
        pairs[gpos[lo] + (idx - lbase2[lo])] = lbuf[idx];
    }
}

// ========== pass B: per-bucket CSR build (one block / bucket) ==========
__global__ void __launch_bounds__(512)
k_buildcsr(const int* __restrict__ pairs, const int* __restrict__ gbase,
           int* __restrict__ ss, int* __restrict__ row, int N) {
    __shared__ int cnt[BN];
    __shared__ int pos[BN];
    __shared__ int part[512];
    int b = blockIdx.x, tid = threadIdx.x;
    int eBeg = gbase[b], eEnd = gbase[b + 1];
    int nodeBase = b << B2;
    for (int l = tid; l < BN; l += 512) cnt[l] = 0;
    __syncthreads();
    for (int e = eBeg + tid; e < eEnd; e += 512)
        atomicAdd(&cnt[((unsigned)pairs[e]) >> 20], 1);
    __syncthreads();
    int l0 = tid * 4;                       // BN/512 == 4
    int c0 = cnt[l0], c1 = cnt[l0 + 1], c2 = cnt[l0 + 2], c3 = cnt[l0 + 3];
    int g = nodeBase + l0;
    int t = c0 + c1 + c2 + c3;
    part[tid] = t;
    __syncthreads();
    for (int off = 1; off < 512; off <<= 1) {
        int v = (tid >= off) ? part[tid - off] : 0;
        __syncthreads();
        part[tid] += v;
        __syncthreads();
    }
    int ex = part[tid] - t;
    pos[l0]     = eBeg + ex;
    pos[l0 + 1] = eBeg + ex + c0;
    pos[l0 + 2] = eBeg + ex + c0 + c1;
    pos[l0 + 3] = eBeg + ex + c0 + c1 + c2;
    int r0 = eBeg + ex + c0, r1 = r0 + c1, r2 = r1 + c2, r3 = r2 + c3;
    if (g + 3 < N) *(int4*)(row + g) = make_int4(r0, r1, r2, r3);
    else {
        if (g < N) row[g] = r0;
        if (g + 1 < N) row[g + 1] = r1;
        if (g + 2 < N) row[g + 2] = r2;
        if (g + 3 < N) row[g + 3] = r3;
    }
    __syncthreads();
    for (int e = eBeg + tid; e < eEnd; e += 512) {
        unsigned v = (unsigned)pairs[e];
        int sl = atomicAdd(&pos[v >> 20], 1);
        ss[sl] = (int)(v & 0xFFFFFu);
    }
}

// ======= node1: dinv from row diffs; y16 = half2(x*dinv) =======
__global__ void k_node1(const float2* __restrict__ x, const int* __restrict__ row,
                        float* __restrict__ dinv, __half2* __restrict__ y16, int N) {
    int i = blockIdx.x * blockDim.x + threadIdx.x;
    if (i >= N) return;
    int end = row[i];
    int beg = (i == 0) ? 0 : row[i - 1];
    float di = rsqrtf((float)(end - beg + 1));
    dinv[i] = di;
    float2 xi = x[i];
    y16[i] = __floats2half2_rn(xi.x * di, xi.y * di);
}

// ========== agg1 (y, 2ch fp16 gathers) + W1 + relu + W2 -> hp2 ==========
__global__ void k_aggf1(const int* __restrict__ row, const int* __restrict__ ss,
                        const __half2* __restrict__ y16, const float2* __restrict__ x,
                        const float* __restrict__ dinv,
                        const float* __restrict__ W1, const float* __restrict__ b1,
                        const float* __restrict__ W2,
                        float4* __restrict__ hp2_32, uint2* __restrict__ hp2_16, int N) {
    int i = blockIdx.x * blockDim.x + threadIdx.x;
    if (i >= N) return;
    int beg = (i == 0) ? 0 : row[i - 1];
    int end = row[i];
    float s0 = 0.f, s1 = 0.f;
    int e = beg;
    for (; e + 3 < end; e += 4) {
        float2 fa = __half22float2(y16[ss[e]]);
        float2 fb = __half22float2(y16[ss[e + 1]]);
        float2 fc = __half22float2(y16[ss[e + 2]]);
        float2 fd = __half22float2(y16[ss[e + 3]]);
        s0 += (fa.x + fb.x) + (fc.x + fd.x);
        s1 += (fa.y + fb.y) + (fc.y + fd.y);
    }
    for (; e < end; ++e) {
        float2 f = __half22float2(y16[ss[e]]);
        s0 += f.x; s1 += f.y;
    }
    float di = dinv[i];
    float2 xi = x[i];
    float ay0 = s0 + xi.x * di;            // self loop in fp32
    float ay1 = s1 + xi.y * di;
    float o0 = fmaxf(di * (ay0 * W1[0] + ay1 * W1[4]) + b1[0], 0.f);
    float o1 = fmaxf(di * (ay0 * W1[1] + ay1 * W1[5]) + b1[1], 0.f);
    float o2 = fmaxf(di * (ay0 * W1[2] + ay1 * W1[6]) + b1[2], 0.f);
    float o3 = fmaxf(di * (ay0 * W1[3] + ay1 * W1[7]) + b1[3], 0.f);
    float h0 = (o0 * W2[0] + o1 * W2[3] + o2 * W2[6] + o3 * W2[9])  * di;
    float h1 = (o0 * W2[1] + o1 * W2[4] + o2 * W2[7] + o3 * W2[10]) * di;
    float h2 = (o0 * W2[2] + o1 * W2[5] + o2 * W2[8] + o3 * W2[11]) * di;
    hp2_32[i] = make_float4(h0, h1, h2, 0.f);
    __half2 lo = __floats2half2_rn(h0, h1);
    __half2 hi = __floats2half2_rn(h2, 0.f);
    uint2 u;
    u.x = *reinterpret_cast<unsigned*>(&lo);
    u.y = *reinterpret_cast<unsigned*>(&hi);
    hp2_16[i] = u;
}

// ========== agg2 (hp2, 3ch fp16 gathers) + sigmoid + MLP -> out ==========
__global__ void k_aggf2(const int* __restrict__ row, const int* __restrict__ ss,
                        const uint2* __restrict__ hp2_16,
                        const float4* __restrict__ hp2_32,
                        const float* __restrict__ dinv, const float* __restrict__ b2,
                        const float* __restrict__ W3, const float* __restrict__ b3,
                        const float* __restrict__ W4, const float* __restrict__ b4,
                        const float* __restrict__ W5, const float* __restrict__ b5,
                        float* __restrict__ out, int N) {
    int i = blockIdx.x * blockDim.x + threadIdx.x;
    if (i >= N) return;
    int beg = (i == 0) ? 0 : row[i - 1];
    int end = row[i];
    float s0 = 0.f, s1 = 0.f, s2 = 0.f;
    for (int e = beg; e < end; ++e) {
        uint2 u = hp2_16[ss[e]];
        __half2 lo = *reinterpret_cast<__half2*>(&u.x);
        __half2 hi = *reinterpret_cast<__half2*>(&u.y);
        float2 flo = __half22float2(lo);
        s0 += flo.x; s1 += flo.y; s2 += __low2float(hi);
    }
    float4 h = hp2_32[i];                  // self loop in fp32
    s0 += h.x; s1 += h.y; s2 += h.z;
    float di = dinv[i];
    float z0 = di * s0 + b2[0];
    float z1 = di * s1 + b2[1];
    float z2 = di * s2 + b2[2];
    float g0 = 1.f / (1.f + expf(-z0));
    float g1 = 1.f / (1.f + expf(-z1));
    float g2 = 1.f / (1.f + expf(-z2));
    float t0 = fmaxf(g0 * W3[0] + g1 * W3[4] + g2 * W3[8]  + b3[0], 0.f);
    float t1 = fmaxf(g0 * W3[1] + g1 * W3[5] + g2 * W3[9]  + b3[1], 0.f);
    float t2 = fmaxf(g0 * W3[2] + g1 * W3[6] + g2 * W3[10] + b3[2], 0.f);
    float t3 = fmaxf(g0 * W3[3] + g1 * W3[7] + g2 * W3[11] + b3[3], 0.f);
    float u0 = fmaxf(t0 * W4[0] + t1 * W4[3] + t2 * W4[6] + t3 * W4[9]  + b4[0], 0.f);
    float u1 = fmaxf(t0 * W4[1] + t1 * W4[4] + t2 * W4[7] + t3 * W4[10] + b4[1], 0.f);
    float u2 = fmaxf(t0 * W4[2] + t1 * W4[5] + t2 * W4[8] + t3 * W4[11] + b4[2], 0.f);
    out[i] = u0 * W5[0] + u1 * W5[1] + u2 * W5[2] + b5[0];
}

// ================= fallback path (round-2 CSR, fp32) =================
__global__ void k_deg(const int* __restrict__ dst, int* __restrict__ deg, int E) {
    int e = blockIdx.x * blockDim.x + threadIdx.x;
    if (e < E) atomicAdd(deg + dst[e], 1);
}
__global__ void k_scan1(const int* __restrict__ deg, int* __restrict__ row,
                        int* __restrict__ bsum, int N) {
    __shared__ int lds[NT];
    int base = blockIdx.x * SCAN_E + threadIdx.x * 4;
    int d0 = 0, d1 = 0, d2 = 0, d3 = 0;
    if (base + 3 < N) {
        int4 v = *(const int4*)(deg + base);
        d0 = v.x; d1 = v.y; d2 = v.z; d3 = v.w;
    } else {
        if (base     < N) d0 = deg[base];
        if (base + 1 < N) d1 = deg[base + 1];
        if (base + 2 < N) d2 = deg[base + 2];
        if (base + 3 < N) d3 = deg[base + 3];
    }
    int t = d0 + d1 + d2 + d3;
    lds[threadIdx.x] = t;
    __syncthreads();
    for (int off = 1; off < NT; off <<= 1) {
        int v = (threadIdx.x >= off) ? lds[threadIdx.x - off] : 0;
        __syncthreads();
        lds[threadIdx.x] += v;
        __syncthreads();
    }
    int excl = lds[threadIdx.x] - t;
    if (threadIdx.x == NT - 1) bsum[blockIdx.x] = lds[NT - 1];
    if (base     < N) row[base]     = excl;
    if (base + 1 < N) row[base + 1] = excl + d0;
    if (base + 2 < N) row[base + 2] = excl + d0 + d1;
    if (base + 3 < N) row[base + 3] = excl + d0 + d1 + d2;
}
__global__ void k_scan2(int* __restrict__ bsum, int M) {
    __shared__ int lds[NT];
    int base = threadIdx.x * 4;
    int d0 = 0, d1 = 0, d2 = 0, d3 = 0;
    if (base     < M) d0 = bsum[base];
    if (base + 1 < M) d1 = bsum[base + 1];
    if (base + 2 < M) d2 = bsum[base + 2];
    if (base + 3 < M) d3 = bsum[base + 3];
    int t = d0 + d1 + d2 + d3;
    lds[threadIdx.x] = t;
    __syncthreads();
    for (int off = 1; off < NT; off <<= 1) {
        int v = (threadIdx.x >= off) ? lds[threadIdx.x - off] : 0;
        __syncthreads();
        lds[threadIdx.x] += v;
        __syncthreads();
    }
    int excl = lds[threadIdx.x] - t;
    if (base     < M) bsum[base]     = excl;
    if (base + 1 < M) bsum[base + 1] = excl + d0;
    if (base + 2 < M) bsum[base + 2] = excl + d0 + d1;
    if (base + 3 < M) bsum[base + 3] = excl + d0 + d1 + d2;
}
__global__ void k_scan3(int* __restrict__ row, const int* __restrict__ bsum, int N) {
    int base = blockIdx.x * SCAN_E + threadIdx.x * 4;
    int add = bsum[blockIdx.x];
    if (base + 3 < N) {
        int4 v = *(int4*)(row + base);
        v.x += add; v.y += add; v.z += add; v.w += add;
        *(int4*)(row + base) = v;
    } else {
        if (base     < N) row[base]     += add;
        if (base + 1 < N) row[base + 1] += add;
        if (base + 2 < N) row[base + 2] += add;
    }
}
__global__ void k_scatter(const int* __restrict__ src, const int* __restrict__ dst,
                          int* __restrict__ row, int* __restrict__ ss, int E) {
    int e = blockIdx.x * blockDim.x + threadIdx.x;
    if (e >= E) return;
    int s = src[e], d = dst[e];
    int slot = atomicAdd(row + d, 1);
    ss[slot] = s;
}
__global__ void k_node1_fb(const float2* __restrict__ x, const int* __restrict__ deg,
                           const float* __restrict__ W1,
                           float* __restrict__ dinv, float4* __restrict__ hp, int N) {
    int i = blockIdx.x * blockDim.x + threadIdx.x;
    if (i >= N) return;
    float2 xi = x[i];
    float di = rsqrtf((float)(deg[i] + 1));
    dinv[i] = di;
    float4 h;
    h.x = (xi.x * W1[0] + xi.y * W1[4]) * di;
    h.y = (xi.x * W1[1] + xi.y * W1[5]) * di;
    h.z = (xi.x * W1[2] + xi.y * W1[6]) * di;
    h.w = (xi.x * W1[3] + xi.y * W1[7]) * di;
    hp[i] = h;
}
__global__ void k_aggf1_fb(const int* __restrict__ row, const int* __restrict__ ss,
                           const float4* __restrict__ hp1, const float* __restrict__ dinv,
                           const float* __restrict__ b1, const float* __restrict__ W2,
                           float4* __restrict__ hp2, int N) {
    int i = blockIdx.x * blockDim.x + threadIdx.x;
    if (i >= N) return;
    int beg = (i == 0) ? 0 : row[i - 1];
    int end = row[i];
    float4 a = hp1[i];
    for (int e = beg; e < end; ++e) {
        float4 ha = hp1[ss[e]];
        a.x += ha.x; a.y += ha.y; a.z += ha.z; a.w += ha.w;
    }
    float di = dinv[i];
    float o0 = fmaxf(di * a.x + b1[0], 0.f);
    float o1 = fmaxf(di * a.y + b1[1], 0.f);
    float o2 = fmaxf(di * a.z + b1[2], 0.f);
    float o3 = fmaxf(di * a.w + b1[3], 0.f);
    float4 h;
    h.x = (o0 * W2[0] + o1 * W2[3] + o2 * W2[6] + o3 * W2[9])  * di;
    h.y = (o0 * W2[1] + o1 * W2[4] + o2 * W2[7] + o3 * W2[10]) * di;
    h.z = (o0 * W2[2] + o1 * W2[5] + o2 * W2[8] + o3 * W2[11]) * di;
    h.w = 0.f;
    hp2[i] = h;
}
__global__ void k_aggf2_fb(const int* __restrict__ row, const int* __restrict__ ss,
                           const float4* __restrict__ hp2, const float* __restrict__ dinv,
                           const float* __restrict__ b2,
                           const float* __restrict__ W3, const float* __restrict__ b3,
                           const float* __restrict__ W4, const float* __restrict__ b4,
                           const float* __restrict__ W5, const float* __restrict__ b5,
                           float* __restrict__ out, int N) {
    int i = blockIdx.x * blockDim.x + threadIdx.x;
    if (i >= N) return;
    int beg = (i == 0) ? 0 : row[i - 1];
    int end = row[i];
    float4 a = hp2[i];
    for (int e = beg; e < end; ++e) {
        float4 ha = hp2[ss[e]];
        a.x += ha.x; a.y += ha.y; a.z += ha.z;
    }
    float di = dinv[i];
    float z0 = di * a.x + b2[0];
    float z1 = di * a.y + b2[1];
    float z2 = di * a.z + b2[2];
    float g0 = 1.f / (1.f + expf(-z0));
    float g1 = 1.f / (1.f + expf(-z1));
    float g2 = 1.f / (1.f + expf(-z2));
    float t0 = fmaxf(g0 * W3[0] + g1 * W3[4] + g2 * W3[8]  + b3[0], 0.f);
    float t1 = fmaxf(g0 * W3[1] + g1 * W3[5] + g2 * W3[9]  + b3[1], 0.f);
    float t2 = fmaxf(g0 * W3[2] + g1 * W3[6] + g2 * W3[10] + b3[2], 0.f);
    float t3 = fmaxf(g0 * W3[3] + g1 * W3[7] + g2 * W3[11] + b3[3], 0.f);
    float u0 = fmaxf(t0 * W4[0] + t1 * W4[3] + t2 * W4[6] + t3 * W4[9]  + b4[0], 0.f);
    float u1 = fmaxf(t0 * W4[1] + t1 * W4[4] + t2 * W4[7] + t3 * W4[10] + b4[1], 0.f);
    float u2 = fmaxf(t0 * W4[2] + t1 * W4[5] + t2 * W4[8] + t3 * W4[11] + b4[2], 0.f);
    out[i] = u0 * W5[0] + u1 * W5[1] + u2 * W5[2] + b5[0];
}

extern "C" void kernel_launch(void* const* d_in, const int* in_sizes, int n_in,
                              void* d_out, int out_size, void* d_ws, size_t ws_size,
                              hipStream_t stream) {
    const float* x  = (const float*)d_in[0];
    const int*   ei = (const int*)d_in[1];
    const float* W1 = (const float*)d_in[2];
    const float* b1 = (const float*)d_in[3];
    const float* W2 = (const float*)d_in[4];
    const float* b2 = (const float*)d_in[5];
    const float* W3 = (const float*)d_in[6];
    const float* b3 = (const float*)d_in[7];
    const float* W4 = (const float*)d_in[8];
    const float* b4 = (const float*)d_in[9];
    const float* W5 = (const float*)d_in[10];
    const float* b5 = (const float*)d_in[11];

    const int N = in_sizes[0] / 2;
    const int E = in_sizes[1] / 2;
    const int* src = ei;
    const int* dst = ei + E;

    const int gbN = (N + NT - 1) / NT;
    const int gbE = (E + NT - 1) / NT;
    const int tiles = (E + TILE - 1) / TILE;
    const int NB = (N + BN - 1) >> B2;

    char* ws = (char*)d_ws;

    // -------- primary: bucketed CSR + fp16 gather arrays --------
    size_t R0 = (size_t)E * 4;
    if (R0 < (size_t)N * 28) R0 = (size_t)N * 28;   // pairs overlays y16/hp2_32/hp2_16
    size_t need1 = R0 + (size_t)E * 4 + (size_t)N * 8 + 3 * (NBMAX + 1) * 4 + 256;

    if (N <= (1 << 20) && NB <= NBMAX && ws_size >= need1) {
        int*     pairs  = (int*)ws;                              // [R0), dead after buildcsr
        __half2* y16    = (__half2*)ws;                          // N*4
        float4*  hp2_32 = (float4*)(ws + (size_t)N * 4);         // N*16
        uint2*   hp2_16 = (uint2*) (ws + (size_t)N * 20);        // N*8
        int*     ss     = (int*)(ws + R0);                       // E*4
        int*     row    = (int*)(ws + R0 + (size_t)E * 4);       // N*4
        float*   dinv   = (float*)(ws + R0 + (size_t)E * 4 + (size_t)N * 4); // N*4
        int*     ghist  = (int*)(ws + R0 + (size_t)E * 4 + (size_t)N * 8);
        int*     gbase  = ghist + (NBMAX + 1);
        int*     gcur   = gbase + (NBMAX + 1);

        hipMemsetAsync(ghist, 0, (NBMAX + 1) * 4, stream);
        k_binhist    <<<tiles, NT, 0, stream>>>(dst, ghist, E);
        k_scanbuckets<<<1, NBMAX, 0, stream>>>(ghist, gbase, gcur, NB, E);
        k_binscatter <<<tiles, NT, 0, stream>>>(src, dst, gcur, pairs, E, NB);
        k_buildcsr   <<<NB, 512, 0, stream>>>(pairs, gbase, ss, row, N);
        k_node1      <<<gbN, NT, 0, stream>>>((const float2*)x, row, dinv, y16, N);
        k_aggf1      <<<gbN, NT, 0, stream>>>(row, ss, y16, (const float2*)x, dinv,
                                              W1, b1, W2, hp2_32, hp2_16, N);
        k_aggf2      <<<gbN, NT, 0, stream>>>(row, ss, hp2_16, hp2_32, dinv, b2,
                                              W3, b3, W4, b4, W5, b5, (float*)d_out, N);
        return;
    }

    // -------- fallback: round-2 global counting-sort CSR (fp32) --------
    const int nScanBlocks = (N + SCAN_E - 1) / SCAN_E;
    size_t need2 = (size_t)N * 44 + (size_t)E * 4 + (size_t)nScanBlocks * 4 + 256;
    if (ws_size >= need2 && nScanBlocks <= NT * 4) {
        float4* hp1  = (float4*)ws;
        float4* hp2  = (float4*)(ws + (size_t)N * 16);
        int*    ss   = (int*)   (ws + (size_t)N * 32);
        int*    deg  = (int*)   (ws + (size_t)N * 32 + (size_t)E * 4);
        int*    row  = (int*)   (ws + (size_t)N * 36 + (size_t)E * 4);
        float*  dinv = (float*) (ws + (size_t)N * 40 + (size_t)E * 4);
        int*    bsum = (int*)   (ws + (size_t)N * 44 + (size_t)E * 4);

        hipMemsetAsync(deg, 0, (size_t)N * 4, stream);
        k_deg     <<<gbE, NT, 0, stream>>>(dst, deg, E);
        k_scan1   <<<nScanBlocks, NT, 0, stream>>>(deg, row, bsum, N);
        k_scan2   <<<1, NT, 0, stream>>>(bsum, nScanBlocks);
        k_scan3   <<<nScanBlocks, NT, 0, stream>>>(row, bsum, N);
        k_node1_fb<<<gbN, NT, 0, stream>>>((const float2*)x, deg, W1, dinv, hp1, N);
        k_scatter <<<gbE, NT, 0, stream>>>(src, dst, row, ss, E);
        k_aggf1_fb<<<gbN, NT, 0, stream>>>(row, ss, hp1, dinv, b1, W2, hp2, N);
        k_aggf2_fb<<<gbN, NT, 0, stream>>>(row, ss, hp2, dinv, b2, W3, b3, W4, b4,
                                           W5, b5, (float*)d_out, N);
    }
}

// Round 6
// 897.795 us; speedup vs baseline: 6.9599x; 1.2500x over previous
//
#include <hip/hip_runtime.h>
#include <hip/hip_bf16.h>
#include <hip/hip_fp16.h>

// GCN, bucket-sorted edge list + per-bucket LDS-accumulator aggregation.
//  - binscatter sorts edges by dst-bucket (B2=10 -> 1024 nodes/bucket) with
//    payload packed to 4B: src | dst_low<<20.  NO intra-bucket sort needed.
//  - per-bucket kernels accumulate into LDS fp32 via ds_add_f32, then run the
//    fused node epilogue. deg/dinv derived per bucket (k_prep).
//  - gather arrays kept <= 4MB (per-XCD L2): layer1 y16 (half2, 4MB);
//    layer2 split into two passes: hp01 (half2, 4MB) then h2 (half, 2MB).
//  All accumulation fp32; self-loop terms fp32.

constexpr int NT = 256;
constexpr int SCAN_E = 1024;   // fallback scan tile
constexpr int B2 = 10;
constexpr int BN = 1 << B2;    // 1024 nodes / bucket
constexpr int NBMAX = 1024;
constexpr int TILE = 4096;     // edges per passA tile

// ================= pass A: bucket histogram =================
__global__ void k_binhist(const int* __restrict__ dst, int* __restrict__ ghist, int E) {
    __shared__ int cnt[NBMAX];
    int t0 = blockIdx.x * TILE;
    for (int l = threadIdx.x; l < NBMAX; l += NT) cnt[l] = 0;
    __syncthreads();
    for (int k = 0; k < TILE / (NT * 4); ++k) {
        int idx = t0 + (k * NT + threadIdx.x) * 4;
        if (idx + 3 < E) {
            int4 d4 = *(const int4*)(dst + idx);
            atomicAdd(&cnt[d4.x >> B2], 1);
            atomicAdd(&cnt[d4.y >> B2], 1);
            atomicAdd(&cnt[d4.z >> B2], 1);
            atomicAdd(&cnt[d4.w >> B2], 1);
        } else {
            for (int j = 0; j < 4; ++j)
                if (idx + j < E) atomicAdd(&cnt[dst[idx + j] >> B2], 1);
        }
    }
    __syncthreads();
    for (int l = threadIdx.x; l < NBMAX; l += NT)
        if (cnt[l]) atomicAdd(&ghist[l], cnt[l]);
}

// ================= scan buckets (1 block of NBMAX thr) =================
__global__ void k_scanbuckets(const int* __restrict__ ghist, int* __restrict__ gbase,
                              int* __restrict__ gcur, int NB, int E) {
    __shared__ int part[NBMAX];
    int tid = threadIdx.x;
    int t = (tid < NB) ? ghist[tid] : 0;
    part[tid] = t;
    __syncthreads();
    for (int off = 1; off < NBMAX; off <<= 1) {
        int v = (tid >= off) ? part[tid - off] : 0;
        __syncthreads();
        part[tid] += v;
        __syncthreads();
    }
    int excl = part[tid] - t;
    if (tid < NB) { gbase[tid] = excl; gcur[tid] = excl; }
    if (tid == 0) gbase[NB] = E;
}

// ========== pass A scatter: bin packed (src | dlow<<20) by dst>>B2 ==========
__global__ void k_binscatter(const int* __restrict__ src, const int* __restrict__ dst,
                             int* __restrict__ gcur, int* __restrict__ pairs,
                             int E, int NB) {
    __shared__ int cnt[NBMAX], cur[NBMAX], gpos[NBMAX];
    __shared__ int lbase2[NBMAX + 1];
    __shared__ int part[NT];
    __shared__ int lbuf[TILE];
    __shared__ int totalSh;
    int t0 = blockIdx.x * TILE;
    int tid = threadIdx.x;
    for (int l = tid; l < NBMAX; l += NT) cnt[l] = 0;
    __syncthreads();
    // count
    for (int k = 0; k < TILE / (NT * 4); ++k) {
        int idx = t0 + (k * NT + tid) * 4;
        if (idx + 3 < E) {
            int4 d4 = *(const int4*)(dst + idx);
            atomicAdd(&cnt[d4.x >> B2], 1);
            atomicAdd(&cnt[d4.y >> B2], 1);
            atomicAdd(&cnt[d4.z >> B2], 1);
            atomicAdd(&cnt[d4.w >> B2], 1);
        } else {
            for (int j = 0; j < 4; ++j)
                if (idx + j < E) atomicAdd(&cnt[dst[idx + j] >> B2], 1);
        }
    }
    __syncthreads();
    // scan 1024 counters with 256 threads (chunk of 4)
    int l0 = tid * 4;
    int c0 = cnt[l0], c1 = cnt[l0 + 1], c2 = cnt[l0 + 2], c3 = cnt[l0 + 3];
    int t = c0 + c1 + c2 + c3;
    part[tid] = t;
    __syncthreads();
    for (int off = 1; off < NT; off <<= 1) {
        int v = (tid >= off) ? part[tid - off] : 0;
        __syncthreads();
        part[tid] += v;
        __syncthreads();
    }
    int ex = part[tid] - t;
    lbase2[l0] = ex;                    cur[l0] = ex;
    lbase2[l0 + 1] = ex + c0;           cur[l0 + 1] = ex + c0;
    lbase2[l0 + 2] = ex + c0 + c1;      cur[l0 + 2] = ex + c0 + c1;
    lbase2[l0 + 3] = ex + c0 + c1 + c2; cur[l0 + 3] = ex + c0 + c1 + c2;
    if (tid == NT - 1) { lbase2[NBMAX] = part[NT - 1]; totalSh = part[NT - 1]; }
    __syncthreads();
    // reserve global ranges
    for (int j = tid; j < NBMAX; j += NT)
        if (j < NB && cnt[j]) gpos[j] = atomicAdd(&gcur[j], cnt[j]);
    __syncthreads();
    // place into LDS sorted by bucket
    for (int k = 0; k < TILE / (NT * 4); ++k) {
        int idx = t0 + (k * NT + tid) * 4;
        if (idx + 3 < E) {
            int4 s4 = *(const int4*)(src + idx);
            int4 d4 = *(const int4*)(dst + idx);
            int b, sl;
            b = d4.x >> B2; sl = atomicAdd(&cur[b], 1);
            lbuf[sl] = s4.x | ((d4.x & (BN - 1)) << 20);
            b = d4.y >> B2; sl = atomicAdd(&cur[b], 1);
            lbuf[sl] = s4.y | ((d4.y & (BN - 1)) << 20);
            b = d4.z >> B2; sl = atomicAdd(&cur[b], 1);
            lbuf[sl] = s4.z | ((d4.z & (BN - 1)) << 20);
            b = d4.w >> B2; sl = atomicAdd(&cur[b], 1);
            lbuf[sl] = s4.w | ((d4.w & (BN - 1)) << 20);
        } else {
            for (int j = 0; j < 4; ++j) {
                if (idx + j < E) {
                    int s = src[idx + j], d = dst[idx + j];
                    int b = d >> B2;
                    int sl = atomicAdd(&cur[b], 1);
                    lbuf[sl] = s | ((d & (BN - 1)) << 20);
                }
            }
        }
    }
    __syncthreads();
    // coalesced copy-out via binary search in lbase2
    int total = totalSh;
    for (int idx = tid; idx < total; idx += NT) {
        int lo = 0, hi = NBMAX - 1;
        while (lo < hi) {
            int mid = (lo + hi + 1) >> 1;
            if (lbase2[mid] <= idx) lo = mid; else hi = mid - 1;
        }
        pairs[gpos[lo] + (idx - lbase2[lo])] = lbuf[idx];
    }
}

// ========== per-bucket prep: deg -> dinv, y16 = half2(x*dinv) ==========
__global__ void k_prep(const int* __restrict__ pairs, const int* __restrict__ gbase,
                       const float2* __restrict__ x,
                       float* __restrict__ dinv, __half2* __restrict__ y16, int N) {
    __shared__ int cnt[BN];
    int b = blockIdx.x, tid = threadIdx.x;
    int eBeg = gbase[b], eEnd = gbase[b + 1];
    for (int l = tid; l < BN; l += NT) cnt[l] = 0;
    __syncthreads();
    for (int e = eBeg + tid; e < eEnd; e += NT)
        atomicAdd(&cnt[((unsigned)pairs[e]) >> 20], 1);
    __syncthreads();
    int base = b << B2;
    for (int j = tid; j < BN; j += NT) {
        int i = base + j;
        if (i < N) {
            float di = rsqrtf((float)(cnt[j] + 1));
            dinv[i] = di;
            float2 xi = x[i];
            y16[i] = __floats2half2_rn(xi.x * di, xi.y * di);
        }
    }
}

// ========== layer1 agg per bucket: LDS fp32 acc + W1/relu/W2 epilogue ==========
__global__ void __launch_bounds__(512)
k_bagg1(const int* __restrict__ pairs, const int* __restrict__ gbase,
        const __half2* __restrict__ y16, const float2* __restrict__ x,
        const float* __restrict__ dinv,
        const float* __restrict__ W1, const float* __restrict__ b1,
        const float* __restrict__ W2,
        float4* __restrict__ hp2full, __half2* __restrict__ hp01,
        __half* __restrict__ h2, int N) {
    __shared__ float acc0[BN], acc1[BN];
    int b = blockIdx.x, tid = threadIdx.x;
    int eBeg = gbase[b], eEnd = gbase[b + 1];
    for (int l = tid; l < BN; l += 512) { acc0[l] = 0.f; acc1[l] = 0.f; }
    __syncthreads();
    for (int e = eBeg + tid; e < eEnd; e += 512) {
        int v = pairs[e];
        int s = v & 0xFFFFF;
        int dl = ((unsigned)v) >> 20;
        float2 f = __half22float2(y16[s]);
        atomicAdd(&acc0[dl], f.x);
        atomicAdd(&acc1[dl], f.y);
    }
    __syncthreads();
    int base = b << B2;
    for (int j = tid; j < BN; j += 512) {
        int i = base + j;
        if (i >= N) continue;
        float di = dinv[i];
        float2 xi = x[i];
        float ay0 = acc0[j] + xi.x * di;   // self loop fp32
        float ay1 = acc1[j] + xi.y * di;
        float o0 = fmaxf(di * (ay0 * W1[0] + ay1 * W1[4]) + b1[0], 0.f);
        float o1 = fmaxf(di * (ay0 * W1[1] + ay1 * W1[5]) + b1[1], 0.f);
        float o2 = fmaxf(di * (ay0 * W1[2] + ay1 * W1[6]) + b1[2], 0.f);
        float o3 = fmaxf(di * (ay0 * W1[3] + ay1 * W1[7]) + b1[3], 0.f);
        float h0 = (o0 * W2[0] + o1 * W2[3] + o2 * W2[6] + o3 * W2[9])  * di;
        float h1 = (o0 * W2[1] + o1 * W2[4] + o2 * W2[7] + o3 * W2[10]) * di;
        float hv2 = (o0 * W2[2] + o1 * W2[5] + o2 * W2[8] + o3 * W2[11]) * di;
        hp2full[i] = make_float4(h0, h1, hv2, 0.f);
        hp01[i] = __floats2half2_rn(h0, h1);
        h2[i] = __float2half_rn(hv2);
    }
}

// ========== layer2 agg pass A: channels 0,1 (4MB gather array) ==========
__global__ void __launch_bounds__(512)
k_bagg2a(const int* __restrict__ pairs, const int* __restrict__ gbase,
         const __half2* __restrict__ hp01, const float4* __restrict__ hp2full,
         float2* __restrict__ part01, int N) {
    __shared__ float acc0[BN], acc1[BN];
    int b = blockIdx.x, tid = threadIdx.x;
    int eBeg = gbase[b], eEnd = gbase[b + 1];
    for (int l = tid; l < BN; l += 512) { acc0[l] = 0.f; acc1[l] = 0.f; }
    __syncthreads();
    for (int e = eBeg + tid; e < eEnd; e += 512) {
        int v = pairs[e];
        int s = v & 0xFFFFF;
        int dl = ((unsigned)v) >> 20;
        float2 f = __half22float2(hp01[s]);
        atomicAdd(&acc0[dl], f.x);
        atomicAdd(&acc1[dl], f.y);
    }
    __syncthreads();
    int base = b << B2;
    for (int j = tid; j < BN; j += 512) {
        int i = base + j;
        if (i >= N) continue;
        float4 hf = hp2full[i];            // self loop fp32
        part01[i] = make_float2(acc0[j] + hf.x, acc1[j] + hf.y);
    }
}

// ========== layer2 agg pass B: channel 2 (2MB gather) + sigmoid + MLP ==========
__global__ void __launch_bounds__(512)
k_bagg2b(const int* __restrict__ pairs, const int* __restrict__ gbase,
         const __half* __restrict__ h2, const float4* __restrict__ hp2full,
         const float2* __restrict__ part01, const float* __restrict__ dinv,
         const float* __restrict__ b2,
         const float* __restrict__ W3, const float* __restrict__ b3,
         const float* __restrict__ W4, const float* __restrict__ b4,
         const float* __restrict__ W5, const float* __restrict__ b5,
         float* __restrict__ out, int N) {
    __shared__ float acc2[BN];
    int b = blockIdx.x, tid = threadIdx.x;
    int eBeg = gbase[b], eEnd = gbase[b + 1];
    for (int l = tid; l < BN; l += 512) acc2[l] = 0.f;
    __syncthreads();
    for (int e = eBeg + tid; e < eEnd; e += 512) {
        int v = pairs[e];
        int s = v & 0xFFFFF;
        int dl = ((unsigned)v) >> 20;
        atomicAdd(&acc2[dl], __half2float(h2[s]));
    }
    __syncthreads();
    int base = b << B2;
    for (int j = tid; j < BN; j += 512) {
        int i = base + j;
        if (i >= N) continue;
        float s2 = acc2[j] + hp2full[i].z; // self loop fp32
        float2 p = part01[i];
        float di = dinv[i];
        float z0 = di * p.x + b2[0];
        float z1 = di * p.y + b2[1];
        float z2 = di * s2 + b2[2];
        float g0 = 1.f / (1.f + expf(-z0));
        float g1 = 1.f / (1.f + expf(-z1));
        float g2 = 1.f / (1.f + expf(-z2));
        float t0 = fmaxf(g0 * W3[0] + g1 * W3[4] + g2 * W3[8]  + b3[0], 0.f);
        float t1 = fmaxf(g0 * W3[1] + g1 * W3[5] + g2 * W3[9]  + b3[1], 0.f);
        float t2 = fmaxf(g0 * W3[2] + g1 * W3[6] + g2 * W3[10] + b3[2], 0.f);
        float t3 = fmaxf(g0 * W3[3] + g1 * W3[7] + g2 * W3[11] + b3[3], 0.f);
        float u0 = fmaxf(t0 * W4[0] + t1 * W4[3] + t2 * W4[6] + t3 * W4[9]  + b4[0], 0.f);
        float u1 = fmaxf(t0 * W4[1] + t1 * W4[4] + t2 * W4[7] + t3 * W4[10] + b4[1], 0.f);
        float u2 = fmaxf(t0 * W4[2] + t1 * W4[5] + t2 * W4[8] + t3 * W4[11] + b4[2], 0.f);
        out[i] = u0 * W5[0] + u1 * W5[1] + u2 * W5[2] + b5[0];
    }
}

// ================= fallback path (round-2 global CSR, fp32) =================
__global__ void k_deg(const int* __restrict__ dst, int* __restrict__ deg, int E) {
    int e = blockIdx.x * blockDim.x + threadIdx.x;
    if (e < E) atomicAdd(deg + dst[e], 1);
}
__global__ void k_scan1(const int* __restrict__ deg, int* __restrict__ row,
                        int* __restrict__ bsum, int N) {
    __shared__ int lds[NT];
    int base = blockIdx.x * SCAN_E + threadIdx.x * 4;
    int d0 = 0, d1 = 0, d2 = 0, d3 = 0;
    if (base + 3 < N) {
        int4 v = *(const int4*)(deg + base);
        d0 = v.x; d1 = v.y; d2 = v.z; d3 = v.w;
    } else {
        if (base     < N) d0 = deg[base];
        if (base + 1 < N) d1 = deg[base + 1];
        if (base + 2 < N) d2 = deg[base + 2];
        if (base + 3 < N) d3 = deg[base + 3];
    }
    int t = d0 + d1 + d2 + d3;
    lds[threadIdx.x] = t;
    __syncthreads();
    for (int off = 1; off < NT; off <<= 1) {
        int v = (threadIdx.x >= off) ? lds[threadIdx.x - off] : 0;
        __syncthreads();
        lds[threadIdx.x] += v;
        __syncthreads();
    }
    int excl = lds[threadIdx.x] - t;
    if (threadIdx.x == NT - 1) bsum[blockIdx.x] = lds[NT - 1];
    if (base     < N) row[base]     = excl;
    if (base + 1 < N) row[base + 1] = excl + d0;
    if (base + 2 < N) row[base + 2] = excl + d0 + d1;
    if (base + 3 < N) row[base + 3] = excl + d0 + d1 + d2;
}
__global__ void k_scan2(int* __restrict__ bsum, int M) {
    __shared__ int lds[NT];
    int base = threadIdx.x * 4;
    int d0 = 0, d1 = 0, d2 = 0, d3 = 0;
    if (base     < M) d0 = bsum[base];
    if (base + 1 < M) d1 = bsum[base + 1];
    if (base + 2 < M) d2 = bsum[base + 2];
    if (base + 3 < M) d3 = bsum[base + 3];
    int t = d0 + d1 + d2 + d3;
    lds[threadIdx.x] = t;
    __syncthreads();
    for (int off = 1; off < NT; off <<= 1) {
        int v = (threadIdx.x >= off) ? lds[threadIdx.x - off] : 0;
        __syncthreads();
        lds[threadIdx.x] += v;
        __syncthreads();
    }
    int excl = lds[threadIdx.x] - t;
    if (base     < M) bsum[base]     = excl;
    if (base + 1 < M) bsum[base + 1] = excl + d0;
    if (base + 2 < M) bsum[base + 2] = excl + d0 + d1;
    if (base + 3 < M) bsum[base + 3] = excl + d0 + d1 + d2;
}
__global__ void k_scan3(int* __restrict__ row, const int* __restrict__ bsum, int N) {
    int base = blockIdx.x * SCAN_E + threadIdx.x * 4;
    int add = bsum[blockIdx.x];
    if (base + 3 < N) {
        int4 v = *(int4*)(row + base);
        v.x += add; v.y += add; v.z += add; v.w += add;
        *(int4*)(row + base) = v;
    } else {
        if (base     < N) row[base]     += add;
        if (base + 1 < N) row[base + 1] += add;
        if (base + 2 < N) row[base + 2] += add;
    }
}
__global__ void k_scatter(const int* __restrict__ src, const int* __restrict__ dst,
                          int* __restrict__ row, int* __restrict__ ss, int E) {
    int e = blockIdx.x * blockDim.x + threadIdx.x;
    if (e >= E) return;
    int s = src[e], d = dst[e];
    int slot = atomicAdd(row + d, 1);
    ss[slot] = s;
}
__global__ void k_node1_fb(const float2* __restrict__ x, const int* __restrict__ deg,
                           const float* __restrict__ W1,
                           float* __restrict__ dinv, float4* __restrict__ hp, int N) {
    int i = blockIdx.x * blockDim.x + threadIdx.x;
    if (i >= N) return;
    float2 xi = x[i];
    float di = rsqrtf((float)(deg[i] + 1));
    dinv[i] = di;
    float4 h;
    h.x = (xi.x * W1[0] + xi.y * W1[4]) * di;
    h.y = (xi.x * W1[1] + xi.y * W1[5]) * di;
    h.z = (xi.x * W1[2] + xi.y * W1[6]) * di;
    h.w = (xi.x * W1[3] + xi.y * W1[7]) * di;
    hp[i] = h;
}
__global__ void k_aggf1_fb(const int* __restrict__ row, const int* __restrict__ ss,
                           const float4* __restrict__ hp1, const float* __restrict__ dinv,
                           const float* __restrict__ b1, const float* __restrict__ W2,
                           float4* __restrict__ hp2, int N) {
    int i = blockIdx.x * blockDim.x + threadIdx.x;
    if (i >= N) return;
    int beg = (i == 0) ? 0 : row[i - 1];
    int end = row[i];
    float4 a = hp1[i];
    for (int e = beg; e < end; ++e) {
        float4 ha = hp1[ss[e]];
        a.x += ha.x; a.y += ha.y; a.z += ha.z; a.w += ha.w;
    }
    float di = dinv[i];
    float o0 = fmaxf(di * a.x + b1[0], 0.f);
    float o1 = fmaxf(di * a.y + b1[1], 0.f);
    float o2 = fmaxf(di * a.z + b1[2], 0.f);
    float o3 = fmaxf(di * a.w + b1[3], 0.f);
    float4 h;
    h.x = (o0 * W2[0] + o1 * W2[3] + o2 * W2[6] + o3 * W2[9])  * di;
    h.y = (o0 * W2[1] + o1 * W2[4] + o2 * W2[7] + o3 * W2[10]) * di;
    h.z = (o0 * W2[2] + o1 * W2[5] + o2 * W2[8] + o3 * W2[11]) * di;
    h.w = 0.f;
    hp2[i] = h;
}
__global__ void k_aggf2_fb(const int* __restrict__ row, const int* __restrict__ ss,
                           const float4* __restrict__ hp2, const float* __restrict__ dinv,
                           const float* __restrict__ b2,
                           const float* __restrict__ W3, const float* __restrict__ b3,
                           const float* __restrict__ W4, const float* __restrict__ b4,
                           const float* __restrict__ W5, const float* __restrict__ b5,
                           float* __restrict__ out, int N) {
    int i = blockIdx.x * blockDim.x + threadIdx.x;
    if (i >= N) return;
    int beg = (i == 0) ? 0 : row[i - 1];
    int end = row[i];
    float4 a = hp2[i];
    for (int e = beg; e < end; ++e) {
        float4 ha = hp2[ss[e]];
        a.x += ha.x; a.y += ha.y; a.z += ha.z;
    }
    float di = dinv[i];
    float z0 = di * a.x + b2[0];
    float z1 = di * a.y + b2[1];
    float z2 = di * a.z + b2[2];
    float g0 = 1.f / (1.f + expf(-z0));
    float g1 = 1.f / (1.f + expf(-z1));
    float g2 = 1.f / (1.f + expf(-z2));
    float t0 = fmaxf(g0 * W3[0] + g1 * W3[4] + g2 * W3[8]  + b3[0], 0.f);
    float t1 = fmaxf(g0 * W3[1] + g1 * W3[5] + g2 * W3[9]  + b3[1], 0.f);
    float t2 = fmaxf(g0 * W3[2] + g1 * W3[6] + g2 * W3[10] + b3[2], 0.f);
    float t3 = fmaxf(g0 * W3[3] + g1 * W3[7] + g2 * W3[11] + b3[3], 0.f);
    float u0 = fmaxf(t0 * W4[0] + t1 * W4[3] + t2 * W4[6] + t3 * W4[9]  + b4[0], 0.f);
    float u1 = fmaxf(t0 * W4[1] + t1 * W4[4] + t2 * W4[7] + t3 * W4[10] + b4[1], 0.f);
    float u2 = fmaxf(t0 * W4[2] + t1 * W4[5] + t2 * W4[8] + t3 * W4[11] + b4[2], 0.f);
    out[i] = u0 * W5[0] + u1 * W5[1] + u2 * W5[2] + b5[0];
}

extern "C" void kernel_launch(void* const* d_in, const int* in_sizes, int n_in,
                              void* d_out, int out_size, void* d_ws, size_t ws_size,
                              hipStream_t stream) {
    const float* x  = (const float*)d_in[0];
    const int*   ei = (const int*)d_in[1];
    const float* W1 = (const float*)d_in[2];
    const float* b1 = (const float*)d_in[3];
    const float* W2 = (const float*)d_in[4];
    const float* b2 = (const float*)d_in[5];
    const float* W3 = (const float*)d_in[6];
    const float* b3 = (const float*)d_in[7];
    const float* W4 = (const float*)d_in[8];
    const float* b4 = (const float*)d_in[9];
    const float* W5 = (const float*)d_in[10];
    const float* b5 = (const float*)d_in[11];

    const int N = in_sizes[0] / 2;
    const int E = in_sizes[1] / 2;
    const int* src = ei;
    const int* dst = ei + E;

    const int gbN = (N + NT - 1) / NT;
    const int gbE = (E + NT - 1) / NT;
    const int tiles = (E + TILE - 1) / TILE;
    const int NB = (N + BN - 1) >> B2;

    char* ws = (char*)d_ws;

    // -------- primary: bucket-sorted pairs + per-bucket LDS aggregation --------
    size_t offPairs = 0;
    size_t offHp2f  = (offPairs + (size_t)E * 4 + 15) & ~(size_t)15;   // float4 align
    size_t offPart  = offHp2f + (size_t)N * 16;                        // float2
    size_t offY16   = offPart + (size_t)N * 8;
    size_t offDinv  = offY16 + (size_t)N * 4;
    size_t offHp01  = offDinv + (size_t)N * 4;
    size_t offH2    = offHp01 + (size_t)N * 4;
    size_t offHist  = (offH2 + (size_t)N * 2 + 15) & ~(size_t)15;
    size_t need1    = offHist + 3 * (NBMAX + 1) * 4 + 64;

    if (N <= (1 << 20) && NB <= NBMAX && ws_size >= need1) {
        int*     pairs   = (int*)(ws + offPairs);
        float4*  hp2full = (float4*)(ws + offHp2f);
        float2*  part01  = (float2*)(ws + offPart);
        __half2* y16     = (__half2*)(ws + offY16);
        float*   dinv    = (float*)(ws + offDinv);
        __half2* hp01    = (__half2*)(ws + offHp01);
        __half*  h2      = (__half*)(ws + offH2);
        int*     ghist   = (int*)(ws + offHist);
        int*     gbase   = ghist + (NBMAX + 1);
        int*     gcur    = gbase + (NBMAX + 1);

        hipMemsetAsync(ghist, 0, (NBMAX + 1) * 4, stream);
        k_binhist    <<<tiles, NT, 0, stream>>>(dst, ghist, E);
        k_scanbuckets<<<1, NBMAX, 0, stream>>>(ghist, gbase, gcur, NB, E);
        k_binscatter <<<tiles, NT, 0, stream>>>(src, dst, gcur, pairs, E, NB);
        k_prep       <<<NB, NT, 0, stream>>>(pairs, gbase, (const float2*)x,
                                             dinv, y16, N);
        k_bagg1      <<<NB, 512, 0, stream>>>(pairs, gbase, y16, (const float2*)x,
                                              dinv, W1, b1, W2, hp2full, hp01, h2, N);
        k_bagg2a     <<<NB, 512, 0, stream>>>(pairs, gbase, hp01, hp2full, part01, N);
        k_bagg2b     <<<NB, 512, 0, stream>>>(pairs, gbase, h2, hp2full, part01, dinv,
                                              b2, W3, b3, W4, b4, W5, b5,
                                              (float*)d_out, N);
        return;
    }

    // -------- fallback: global counting-sort CSR (fp32) --------
    const int nScanBlocks = (N + SCAN_E - 1) / SCAN_E;
    size_t need2 = (size_t)N * 44 + (size_t)E * 4 + (size_t)nScanBlocks * 4 + 256;
    if (ws_size >= need2 && nScanBlocks <= NT * 4) {
        float4* hp1  = (float4*)ws;
        float4* hp2  = (float4*)(ws + (size_t)N * 16);
        int*    ss   = (int*)   (ws + (size_t)N * 32);
        int*    deg  = (int*)   (ws + (size_t)N * 32 + (size_t)E * 4);
        int*    row  = (int*)   (ws + (size_t)N * 36 + (size_t)E * 4);
        float*  dinv = (float*) (ws + (size_t)N * 40 + (size_t)E * 4);
        int*    bsum = (int*)   (ws + (size_t)N * 44 + (size_t)E * 4);

        hipMemsetAsync(deg, 0, (size_t)N * 4, stream);
        k_deg     <<<gbE, NT, 0, stream>>>(dst, deg, E);
        k_scan1   <<<nScanBlocks, NT, 0, stream>>>(deg, row, bsum, N);
        k_scan2   <<<1, NT, 0, stream>>>(bsum, nScanBlocks);
        k_scan3   <<<nScanBlocks, NT, 0, stream>>>(row, bsum, N);
        k_node1_fb<<<gbN, NT, 0, stream>>>((const float2*)x, deg, W1, dinv, hp1, N);
        k_scatter <<<gbE, NT, 0, stream>>>(src, dst, row, ss, E);
        k_aggf1_fb<<<gbN, NT, 0, stream>>>(row, ss, hp1, dinv, b1, W2, hp2, N);
        k_aggf2_fb<<<gbN, NT, 0, stream>>>(row, ss, hp2, dinv, b2, W3, b3, W4, b4,
                                           W5, b5, (float*)d_out, N);
    }
}

// Round 7
// 818.666 us; speedup vs baseline: 7.6327x; 1.0967x over previous
//
#include <hip/hip_runtime.h>
#include <hip/hip_bf16.h>
#include <hip/hip_fp16.h>

// GCN, bucket-sorted edge list + per-bucket LDS-accumulator aggregation.
//  - B2=11: 2048 nodes/bucket, 489 buckets. TILE=8192 edges per partition tile
//    -> avg 16.8-edge runs at copy-out (write-coalescing).
//  - bucket segments padded to x4 edges (16B) with sentinel 0x80000000 so all
//    consumers stream pairs as aligned int4 (4 independent gathers in flight).
//  - gather arrays <= 4MB (per-XCD L2): y16 half2 4MB; layer2 split: hp01
//    (half2 4MB) then h2 (half 2MB). fp32 accumulate, fp32 self-loop.

constexpr int NT = 256;
constexpr int SCAN_E = 1024;   // fallback scan tile
constexpr int B2 = 11;
constexpr int BN = 1 << B2;    // 2048 nodes / bucket
constexpr int NBMAX = 512;
constexpr int TILE = 8192;     // edges per passA tile
constexpr int SENT = (int)0x80000000;

// ================= pass A: bucket histogram =================
__global__ void k_binhist(const int* __restrict__ dst, int* __restrict__ ghist, int E) {
    __shared__ int cnt[NBMAX];
    int t0 = blockIdx.x * TILE;
    for (int l = threadIdx.x; l < NBMAX; l += NT) cnt[l] = 0;
    __syncthreads();
    for (int k = 0; k < TILE / (NT * 4); ++k) {
        int idx = t0 + (k * NT + threadIdx.x) * 4;
        if (idx + 3 < E) {
            int4 d4 = *(const int4*)(dst + idx);
            atomicAdd(&cnt[d4.x >> B2], 1);
            atomicAdd(&cnt[d4.y >> B2], 1);
            atomicAdd(&cnt[d4.z >> B2], 1);
            atomicAdd(&cnt[d4.w >> B2], 1);
        } else {
            for (int j = 0; j < 4; ++j)
                if (idx + j < E) atomicAdd(&cnt[dst[idx + j] >> B2], 1);
        }
    }
    __syncthreads();
    for (int l = threadIdx.x; l < NBMAX; l += NT)
        if (cnt[l]) atomicAdd(&ghist[l], cnt[l]);
}

// ===== scan buckets (1 block of NBMAX thr); pad sizes to x4 for alignment =====
__global__ void k_scanbuckets(const int* __restrict__ ghist, int* __restrict__ gbase,
                              int* __restrict__ gcur, int NB) {
    __shared__ int part[NBMAX];
    int tid = threadIdx.x;
    int t = (tid < NB) ? ghist[tid] : 0;
    int p = (t + 3) & ~3;                  // padded size
    part[tid] = p;
    __syncthreads();
    for (int off = 1; off < NBMAX; off <<= 1) {
        int v = (tid >= off) ? part[tid - off] : 0;
        __syncthreads();
        part[tid] += v;
        __syncthreads();
    }
    int excl = part[tid] - p;
    if (tid < NB) { gbase[tid] = excl; gcur[tid] = excl; }
    if (tid == 0) gbase[NB] = part[NBMAX - 1];
}

// ===== fill pad gaps with sentinels (disjoint from binscatter's writes) =====
__global__ void k_pad(const int* __restrict__ ghist, const int* __restrict__ gbase,
                      int* __restrict__ pairs, int NB) {
    int b = threadIdx.x;
    if (b >= NB) return;
    int e = gbase[b] + ghist[b];
    int nxt = gbase[b + 1];
    for (; e < nxt; ++e) pairs[e] = SENT;
}

// ========== pass A scatter: bin packed (src | dlow<<20) by dst>>B2 ==========
__global__ void k_binscatter(const int* __restrict__ src, const int* __restrict__ dst,
                             int* __restrict__ gcur, int* __restrict__ pairs,
                             int E, int NB) {
    __shared__ int cnt[NBMAX], cur[NBMAX], gpos[NBMAX];
    __shared__ int lbase2[NBMAX + 1];
    __shared__ int part[NT];
    __shared__ int lbuf[TILE];
    __shared__ int totalSh;
    int t0 = blockIdx.x * TILE;
    int tid = threadIdx.x;
    for (int l = tid; l < NBMAX; l += NT) cnt[l] = 0;
    __syncthreads();
    // count
    for (int k = 0; k < TILE / (NT * 4); ++k) {
        int idx = t0 + (k * NT + tid) * 4;
        if (idx + 3 < E) {
            int4 d4 = *(const int4*)(dst + idx);
            atomicAdd(&cnt[d4.x >> B2], 1);
            atomicAdd(&cnt[d4.y >> B2], 1);
            atomicAdd(&cnt[d4.z >> B2], 1);
            atomicAdd(&cnt[d4.w >> B2], 1);
        } else {
            for (int j = 0; j < 4; ++j)
                if (idx + j < E) atomicAdd(&cnt[dst[idx + j] >> B2], 1);
        }
    }
    __syncthreads();
    // scan 512 counters with 256 threads (chunk of 2)
    int c0 = cnt[2 * tid], c1 = cnt[2 * tid + 1];
    int t = c0 + c1;
    part[tid] = t;
    __syncthreads();
    for (int off = 1; off < NT; off <<= 1) {
        int v = (tid >= off) ? part[tid - off] : 0;
        __syncthreads();
        part[tid] += v;
        __syncthreads();
    }
    int ex = part[tid] - t;
    lbase2[2 * tid] = ex;          cur[2 * tid] = ex;
    lbase2[2 * tid + 1] = ex + c0; cur[2 * tid + 1] = ex + c0;
    if (tid == NT - 1) { lbase2[NBMAX] = part[NT - 1]; totalSh = part[NT - 1]; }
    __syncthreads();
    // reserve global ranges
    for (int j = tid; j < NBMAX; j += NT)
        if (j < NB && cnt[j]) gpos[j] = atomicAdd(&gcur[j], cnt[j]);
    __syncthreads();
    // place into LDS sorted by bucket
    for (int k = 0; k < TILE / (NT * 4); ++k) {
        int idx = t0 + (k * NT + tid) * 4;
        if (idx + 3 < E) {
            int4 s4 = *(const int4*)(src + idx);
            int4 d4 = *(const int4*)(dst + idx);
            int b, sl;
            b = d4.x >> B2; sl = atomicAdd(&cur[b], 1);
            lbuf[sl] = s4.x | ((d4.x & (BN - 1)) << 20);
            b = d4.y >> B2; sl = atomicAdd(&cur[b], 1);
            lbuf[sl] = s4.y | ((d4.y & (BN - 1)) << 20);
            b = d4.z >> B2; sl = atomicAdd(&cur[b], 1);
            lbuf[sl] = s4.z | ((d4.z & (BN - 1)) << 20);
            b = d4.w >> B2; sl = atomicAdd(&cur[b], 1);
            lbuf[sl] = s4.w | ((d4.w & (BN - 1)) << 20);
        } else {
            for (int j = 0; j < 4; ++j) {
                if (idx + j < E) {
                    int s = src[idx + j], d = dst[idx + j];
                    int b = d >> B2;
                    int sl = atomicAdd(&cur[b], 1);
                    lbuf[sl] = s | ((d & (BN - 1)) << 20);
                }
            }
        }
    }
    __syncthreads();
    // coalesced copy-out via binary search in lbase2
    int total = totalSh;
    for (int idx = tid; idx < total; idx += NT) {
        int lo = 0, hi = NBMAX - 1;
        while (lo < hi) {
            int mid = (lo + hi + 1) >> 1;
            if (lbase2[mid] <= idx) lo = mid; else hi = mid - 1;
        }
        pairs[gpos[lo] + (idx - lbase2[lo])] = lbuf[idx];
    }
}

// ========== per-bucket prep: deg -> dinv, y16 = half2(x*dinv) ==========
__global__ void __launch_bounds__(512)
k_prep(const int* __restrict__ pairs, const int* __restrict__ gbase,
       const float2* __restrict__ x,
       float* __restrict__ dinv, __half2* __restrict__ y16, int N) {
    __shared__ int cnt[BN];
    int b = blockIdx.x, tid = threadIdx.x;
    int eBeg = gbase[b], eEnd = gbase[b + 1];
    for (int l = tid; l < BN; l += 512) cnt[l] = 0;
    __syncthreads();
    for (int idx = eBeg + (tid << 2); idx < eEnd; idx += 512 * 4) {
        int4 v4 = *(const int4*)(pairs + idx);
        if (v4.x >= 0) atomicAdd(&cnt[((unsigned)v4.x) >> 20], 1);
        if (v4.y >= 0) atomicAdd(&cnt[((unsigned)v4.y) >> 20], 1);
        if (v4.z >= 0) atomicAdd(&cnt[((unsigned)v4.z) >> 20], 1);
        if (v4.w >= 0) atomicAdd(&cnt[((unsigned)v4.w) >> 20], 1);
    }
    __syncthreads();
    int base = b << B2;
    for (int j = tid; j < BN; j += 512) {
        int i = base + j;
        if (i < N) {
            float di = rsqrtf((float)(cnt[j] + 1));
            dinv[i] = di;
            float2 xi = x[i];
            y16[i] = __floats2half2_rn(xi.x * di, xi.y * di);
        }
    }
}

// ========== layer1 agg per bucket: LDS fp32 acc + W1/relu/W2 epilogue ==========
__global__ void __launch_bounds__(512)
k_bagg1(const int* __restrict__ pairs, const int* __restrict__ gbase,
        const __half2* __restrict__ y16, const float2* __restrict__ x,
        const float* __restrict__ dinv,
        const float* __restrict__ W1, const float* __restrict__ b1,
        const float* __restrict__ W2,
        float4* __restrict__ hp2full, __half2* __restrict__ hp01,
        __half* __restrict__ h2, int N) {
    __shared__ float acc0[BN], acc1[BN];
    int b = blockIdx.x, tid = threadIdx.x;
    int eBeg = gbase[b], eEnd = gbase[b + 1];
    for (int l = tid; l < BN; l += 512) { acc0[l] = 0.f; acc1[l] = 0.f; }
    __syncthreads();
    for (int idx = eBeg + (tid << 2); idx < eEnd; idx += 512 * 4) {
        int4 v4 = *(const int4*)(pairs + idx);
        // 4 independent gathers in flight
        if (v4.x >= 0) {
            float2 f = __half22float2(y16[v4.x & 0xFFFFF]);
            int dl = ((unsigned)v4.x) >> 20;
            atomicAdd(&acc0[dl], f.x); atomicAdd(&acc1[dl], f.y);
        }
        if (v4.y >= 0) {
            float2 f = __half22float2(y16[v4.y & 0xFFFFF]);
            int dl = ((unsigned)v4.y) >> 20;
            atomicAdd(&acc0[dl], f.x); atomicAdd(&acc1[dl], f.y);
        }
        if (v4.z >= 0) {
            float2 f = __half22float2(y16[v4.z & 0xFFFFF]);
            int dl = ((unsigned)v4.z) >> 20;
            atomicAdd(&acc0[dl], f.x); atomicAdd(&acc1[dl], f.y);
        }
        if (v4.w >= 0) {
            float2 f = __half22float2(y16[v4.w & 0xFFFFF]);
            int dl = ((unsigned)v4.w) >> 20;
            atomicAdd(&acc0[dl], f.x); atomicAdd(&acc1[dl], f.y);
        }
    }
    __syncthreads();
    int base = b << B2;
    for (int j = tid; j < BN; j += 512) {
        int i = base + j;
        if (i >= N) continue;
        float di = dinv[i];
        float2 xi = x[i];
        float ay0 = acc0[j] + xi.x * di;   // self loop fp32
        float ay1 = acc1[j] + xi.y * di;
        float o0 = fmaxf(di * (ay0 * W1[0] + ay1 * W1[4]) + b1[0], 0.f);
        float o1 = fmaxf(di * (ay0 * W1[1] + ay1 * W1[5]) + b1[1], 0.f);
        float o2 = fmaxf(di * (ay0 * W1[2] + ay1 * W1[6]) + b1[2], 0.f);
        float o3 = fmaxf(di * (ay0 * W1[3] + ay1 * W1[7]) + b1[3], 0.f);
        float h0 = (o0 * W2[0] + o1 * W2[3] + o2 * W2[6] + o3 * W2[9])  * di;
        float h1 = (o0 * W2[1] + o1 * W2[4] + o2 * W2[7] + o3 * W2[10]) * di;
        float hv2 = (o0 * W2[2] + o1 * W2[5] + o2 * W2[8] + o3 * W2[11]) * di;
        hp2full[i] = make_float4(h0, h1, hv2, 0.f);
        hp01[i] = __floats2half2_rn(h0, h1);
        h2[i] = __float2half_rn(hv2);
    }
}

// ========== layer2 agg pass A: channels 0,1 (4MB gather array) ==========
__global__ void __launch_bounds__(512)
k_bagg2a(const int* __restrict__ pairs, const int* __restrict__ gbase,
         const __half2* __restrict__ hp01, const float4* __restrict__ hp2full,
         float2* __restrict__ part01, int N) {
    __shared__ float acc0[BN], acc1[BN];
    int b = blockIdx.x, tid = threadIdx.x;
    int eBeg = gbase[b], eEnd = gbase[b + 1];
    for (int l = tid; l < BN; l += 512) { acc0[l] = 0.f; acc1[l] = 0.f; }
    __syncthreads();
    for (int idx = eBeg + (tid << 2); idx < eEnd; idx += 512 * 4) {
        int4 v4 = *(const int4*)(pairs + idx);
        if (v4.x >= 0) {
            float2 f = __half22float2(hp01[v4.x & 0xFFFFF]);
            int dl = ((unsigned)v4.x) >> 20;
            atomicAdd(&acc0[dl], f.x); atomicAdd(&acc1[dl], f.y);
        }
        if (v4.y >= 0) {
            float2 f = __half22float2(hp01[v4.y & 0xFFFFF]);
            int dl = ((unsigned)v4.y) >> 20;
            atomicAdd(&acc0[dl], f.x); atomicAdd(&acc1[dl], f.y);
        }
        if (v4.z >= 0) {
            float2 f = __half22float2(hp01[v4.z & 0xFFFFF]);
            int dl = ((unsigned)v4.z) >> 20;
            atomicAdd(&acc0[dl], f.x); atomicAdd(&acc1[dl], f.y);
        }
        if (v4.w >= 0) {
            float2 f = __half22float2(hp01[v4.w & 0xFFFFF]);
            int dl = ((unsigned)v4.w) >> 20;
            atomicAdd(&acc0[dl], f.x); atomicAdd(&acc1[dl], f.y);
        }
    }
    __syncthreads();
    int base = b << B2;
    for (int j = tid; j < BN; j += 512) {
        int i = base + j;
        if (i >= N) continue;
        float4 hf = hp2full[i];            // self loop fp32
        part01[i] = make_float2(acc0[j] + hf.x, acc1[j] + hf.y);
    }
}

// ========== layer2 agg pass B: channel 2 (2MB gather) + sigmoid + MLP ==========
__global__ void __launch_bounds__(512)
k_bagg2b(const int* __restrict__ pairs, const int* __restrict__ gbase,
         const __half* __restrict__ h2, const float4* __restrict__ hp2full,
         const float2* __restrict__ part01, const float* __restrict__ dinv,
         const float* __restrict__ b2,
         const float* __restrict__ W3, const float* __restrict__ b3,
         const float* __restrict__ W4, const float* __restrict__ b4,
         const float* __restrict__ W5, const float* __restrict__ b5,
         float* __restrict__ out, int N) {
    __shared__ float acc2[BN];
    int b = blockIdx.x, tid = threadIdx.x;
    int eBeg = gbase[b], eEnd = gbase[b + 1];
    for (int l = tid; l < BN; l += 512) acc2[l] = 0.f;
    __syncthreads();
    for (int idx = eBeg + (tid << 2); idx < eEnd; idx += 512 * 4) {
        int4 v4 = *(const int4*)(pairs + idx);
        if (v4.x >= 0)
            atomicAdd(&acc2[((unsigned)v4.x) >> 20], __half2float(h2[v4.x & 0xFFFFF]));
        if (v4.y >= 0)
            atomicAdd(&acc2[((unsigned)v4.y) >> 20], __half2float(h2[v4.y & 0xFFFFF]));
        if (v4.z >= 0)
            atomicAdd(&acc2[((unsigned)v4.z) >> 20], __half2float(h2[v4.z & 0xFFFFF]));
        if (v4.w >= 0)
            atomicAdd(&acc2[((unsigned)v4.w) >> 20], __half2float(h2[v4.w & 0xFFFFF]));
    }
    __syncthreads();
    int base = b << B2;
    for (int j = tid; j < BN; j += 512) {
        int i = base + j;
        if (i >= N) continue;
        float s2 = acc2[j] + hp2full[i].z; // self loop fp32
        float2 p = part01[i];
        float di = dinv[i];
        float z0 = di * p.x + b2[0];
        float z1 = di * p.y + b2[1];
        float z2 = di * s2 + b2[2];
        float g0 = 1.f / (1.f + expf(-z0));
        float g1 = 1.f / (1.f + expf(-z1));
        float g2 = 1.f / (1.f + expf(-z2));
        float t0 = fmaxf(g0 * W3[0] + g1 * W3[4] + g2 * W3[8]  + b3[0], 0.f);
        float t1 = fmaxf(g0 * W3[1] + g1 * W3[5] + g2 * W3[9]  + b3[1], 0.f);
        float t2 = fmaxf(g0 * W3[2] + g1 * W3[6] + g2 * W3[10] + b3[2], 0.f);
        float t3 = fmaxf(g0 * W3[3] + g1 * W3[7] + g2 * W3[11] + b3[3], 0.f);
        float u0 = fmaxf(t0 * W4[0] + t1 * W4[3] + t2 * W4[6] + t3 * W4[9]  + b4[0], 0.f);
        float u1 = fmaxf(t0 * W4[1] + t1 * W4[4] + t2 * W4[7] + t3 * W4[10] + b4[1], 0.f);
        float u2 = fmaxf(t0 * W4[2] + t1 * W4[5] + t2 * W4[8] + t3 * W4[11] + b4[2], 0.f);
        out[i] = u0 * W5[0] + u1 * W5[1] + u2 * W5[2] + b5[0];
    }
}

// ================= fallback path (round-2 global CSR, fp32) =================
__global__ void k_deg(const int* __restrict__ dst, int* __restrict__ deg, int E) {
    int e = blockIdx.x * blockDim.x + threadIdx.x;
    if (e < E) atomicAdd(deg + dst[e], 1);
}
__global__ void k_scan1(const int* __restrict__ deg, int* __restrict__ row,
                        int* __restrict__ bsum, int N) {
    __shared__ int lds[NT];
    int base = blockIdx.x * SCAN_E + threadIdx.x * 4;
    int d0 = 0, d1 = 0, d2 = 0, d3 = 0;
    if (base + 3 < N) {
        int4 v = *(const int4*)(deg + base);
        d0 = v.x; d1 = v.y; d2 = v.z; d3 = v.w;
    } else {
        if (base     < N) d0 = deg[base];
        if (base + 1 < N) d1 = deg[base + 1];
        if (base + 2 < N) d2 = deg[base + 2];
        if (base + 3 < N) d3 = deg[base + 3];
    }
    int t = d0 + d1 + d2 + d3;
    lds[threadIdx.x] = t;
    __syncthreads();
    for (int off = 1; off < NT; off <<= 1) {
        int v = (threadIdx.x >= off) ? lds[threadIdx.x - off] : 0;
        __syncthreads();
        lds[threadIdx.x] += v;
        __syncthreads();
    }
    int excl = lds[threadIdx.x] - t;
    if (threadIdx.x == NT - 1) bsum[blockIdx.x] = lds[NT - 1];
    if (base     < N) row[base]     = excl;
    if (base + 1 < N) row[base + 1] = excl + d0;
    if (base + 2 < N) row[base + 2] = excl + d0 + d1;
    if (base + 3 < N) row[base + 3] = excl + d0 + d1 + d2;
}
__global__ void k_scan2(int* __restrict__ bsum, int M) {
    __shared__ int lds[NT];
    int base = threadIdx.x * 4;
    int d0 = 0, d1 = 0, d2 = 0, d3 = 0;
    if (base     < M) d0 = bsum[base];
    if (base + 1 < M) d1 = bsum[base + 1];
    if (base + 2 < M) d2 = bsum[base + 2];
    if (base + 3 < M) d3 = bsum[base + 3];
    int t = d0 + d1 + d2 + d3;
    lds[threadIdx.x] = t;
    __syncthreads();
    for (int off = 1; off < NT; off <<= 1) {
        int v = (threadIdx.x >= off) ? lds[threadIdx.x - off] : 0;
        __syncthreads();
        lds[threadIdx.x] += v;
        __syncthreads();
    }
    int excl = lds[threadIdx.x] - t;
    if (base     < M) bsum[base]     = excl;
    if (base + 1 < M) bsum[base + 1] = excl + d0;
    if (base + 2 < M) bsum[base + 2] = excl + d0 + d1;
    if (base + 3 < M) bsum[base + 3] = excl + d0 + d1 + d2;
}
__global__ void k_scan3(int* __restrict__ row, const int* __restrict__ bsum, int N) {
    int base = blockIdx.x * SCAN_E + threadIdx.x * 4;
    int add = bsum[blockIdx.x];
    if (base + 3 < N) {
        int4 v = *(int4*)(row + base);
        v.x += add; v.y += add; v.z += add; v.w += add;
        *(int4*)(row + base) = v;
    } else {
        if (base     < N) row[base]     += add;
        if (base + 1 < N) row[base + 1] += add;
        if (base + 2 < N) row[base + 2] += add;
    }
}
__global__ void k_scatter(const int* __restrict__ src, const int* __restrict__ dst,
                          int* __restrict__ row, int* __restrict__ ss, int E) {
    int e = blockIdx.x * blockDim.x + threadIdx.x;
    if (e >= E) return;
    int s = src[e], d = dst[e];
    int slot = atomicAdd(row + d, 1);
    ss[slot] = s;
}
__global__ void k_node1_fb(const float2* __restrict__ x, const int* __restrict__ deg,
                           const float* __restrict__ W1,
                           float* __restrict__ dinv, float4* __restrict__ hp, int N) {
    int i = blockIdx.x * blockDim.x + threadIdx.x;
    if (i >= N) return;
    float2 xi = x[i];
    float di = rsqrtf((float)(deg[i] + 1));
    dinv[i] = di;
    float4 h;
    h.x = (xi.x * W1[0] + xi.y * W1[4]) * di;
    h.y = (xi.x * W1[1] + xi.y * W1[5]) * di;
    h.z = (xi.x * W1[2] + xi.y * W1[6]) * di;
    h.w = (xi.x * W1[3] + xi.y * W1[7]) * di;
    hp[i] = h;
}
__global__ void k_aggf1_fb(const int* __restrict__ row, const int* __restrict__ ss,
                           const float4* __restrict__ hp1, const float* __restrict__ dinv,
                           const float* __restrict__ b1, const float* __restrict__ W2,
                           float4* __restrict__ hp2, int N) {
    int i = blockIdx.x * blockDim.x + threadIdx.x;
    if (i >= N) return;
    int beg = (i == 0) ? 0 : row[i - 1];
    int end = row[i];
    float4 a = hp1[i];
    for (int e = beg; e < end; ++e) {
        float4 ha = hp1[ss[e]];
        a.x += ha.x; a.y += ha.y; a.z += ha.z; a.w += ha.w;
    }
    float di = dinv[i];
    float o0 = fmaxf(di * a.x + b1[0], 0.f);
    float o1 = fmaxf(di * a.y + b1[1], 0.f);
    float o2 = fmaxf(di * a.z + b1[2], 0.f);
    float o3 = fmaxf(di * a.w + b1[3], 0.f);
    float4 h;
    h.x = (o0 * W2[0] + o1 * W2[3] + o2 * W2[6] + o3 * W2[9])  * di;
    h.y = (o0 * W2[1] + o1 * W2[4] + o2 * W2[7] + o3 * W2[10]) * di;
    h.z = (o0 * W2[2] + o1 * W2[5] + o2 * W2[8] + o3 * W2[11]) * di;
    h.w = 0.f;
    hp2[i] = h;
}
__global__ void k_aggf2_fb(const int* __restrict__ row, const int* __restrict__ ss,
                           const float4* __restrict__ hp2, const float* __restrict__ dinv,
                           const float* __restrict__ b2,
                           const float* __restrict__ W3, const float* __restrict__ b3,
                           const float* __restrict__ W4, const float* __restrict__ b4,
                           const float* __restrict__ W5, const float* __restrict__ b5,
                           float* __restrict__ out, int N) {
    int i = blockIdx.x * blockDim.x + threadIdx.x;
    if (i >= N) return;
    int beg = (i == 0) ? 0 : row[i - 1];
    int end = row[i];
    float4 a = hp2[i];
    for (int e = beg; e < end; ++e) {
        float4 ha = hp2[ss[e]];
        a.x += ha.x; a.y += ha.y; a.z += ha.z;
    }
    float di = dinv[i];
    float z0 = di * a.x + b2[0];
    float z1 = di * a.y + b2[1];
    float z2 = di * a.z + b2[2];
    float g0 = 1.f / (1.f + expf(-z0));
    float g1 = 1.f / (1.f + expf(-z1));
    float g2 = 1.f / (1.f + expf(-z2));
    float t0 = fmaxf(g0 * W3[0] + g1 * W3[4] + g2 * W3[8]  + b3[0], 0.f);
    float t1 = fmaxf(g0 * W3[1] + g1 * W3[5] + g2 * W3[9]  + b3[1], 0.f);
    float t2 = fmaxf(g0 * W3[2] + g1 * W3[6] + g2 * W3[10] + b3[2], 0.f);
    float t3 = fmaxf(g0 * W3[3] + g1 * W3[7] + g2 * W3[11] + b3[3], 0.f);
    float u0 = fmaxf(t0 * W4[0] + t1 * W4[3] + t2 * W4[6] + t3 * W4[9]  + b4[0], 0.f);
    float u1 = fmaxf(t0 * W4[1] + t1 * W4[4] + t2 * W4[7] + t3 * W4[10] + b4[1], 0.f);
    float u2 = fmaxf(t0 * W4[2] + t1 * W4[5] + t2 * W4[8] + t3 * W4[11] + b4[2], 0.f);
    out[i] = u0 * W5[0] + u1 * W5[1] + u2 * W5[2] + b5[0];
}

extern "C" void kernel_launch(void* const* d_in, const int* in_sizes, int n_in,
                              void* d_out, int out_size, void* d_ws, size_t ws_size,
                              hipStream_t stream) {
    const float* x  = (const float*)d_in[0];
    const int*   ei = (const int*)d_in[1];
    const float* W1 = (const float*)d_in[2];
    const float* b1 = (const float*)d_in[3];
    const float* W2 = (const float*)d_in[4];
    const float* b2 = (const float*)d_in[5];
    const float* W3 = (const float*)d_in[6];
    const float* b3 = (const float*)d_in[7];
    const float* W4 = (const float*)d_in[8];
    const float* b4 = (const float*)d_in[9];
    const float* W5 = (const float*)d_in[10];
    const float* b5 = (const float*)d_in[11];

    const int N = in_sizes[0] / 2;
    const int E = in_sizes[1] / 2;
    const int* src = ei;
    const int* dst = ei + E;

    const int gbN = (N + NT - 1) / NT;
    const int gbE = (E + NT - 1) / NT;
    const int tiles = (E + TILE - 1) / TILE;
    const int NB = (N + BN - 1) >> B2;

    char* ws = (char*)d_ws;

    // -------- primary: bucket-sorted pairs (padded x4) + per-bucket LDS agg ----
    size_t szPairs = (size_t)(E + 4 * NBMAX) * 4;
    size_t offHp2f = (szPairs + 15) & ~(size_t)15;
    size_t offPart = offHp2f + (size_t)N * 16;
    size_t offY16  = offPart + (size_t)N * 8;
    size_t offDinv = offY16 + (size_t)N * 4;
    size_t offHp01 = offDinv + (size_t)N * 4;
    size_t offH2   = offHp01 + (size_t)N * 4;
    size_t offHist = (offH2 + (size_t)N * 2 + 15) & ~(size_t)15;
    size_t need1   = offHist + 3 * (NBMAX + 1) * 4 + 64;

    if (N <= (1 << 20) && NB <= NBMAX && ws_size >= need1) {
        int*     pairs   = (int*)ws;
        float4*  hp2full = (float4*)(ws + offHp2f);
        float2*  part01  = (float2*)(ws + offPart);
        __half2* y16     = (__half2*)(ws + offY16);
        float*   dinv    = (float*)(ws + offDinv);
        __half2* hp01    = (__half2*)(ws + offHp01);
        __half*  h2      = (__half*)(ws + offH2);
        int*     ghist   = (int*)(ws + offHist);
        int*     gbase   = ghist + (NBMAX + 1);
        int*     gcur    = gbase + (NBMAX + 1);

        hipMemsetAsync(ghist, 0, (NBMAX + 1) * 4, stream);
        k_binhist    <<<tiles, NT, 0, stream>>>(dst, ghist, E);
        k_scanbuckets<<<1, NBMAX, 0, stream>>>(ghist, gbase, gcur, NB);
        k_pad        <<<1, NBMAX, 0, stream>>>(ghist, gbase, pairs, NB);
        k_binscatter <<<tiles, NT, 0, stream>>>(src, dst, gcur, pairs, E, NB);
        k_prep       <<<NB, 512, 0, stream>>>(pairs, gbase, (const float2*)x,
                                              dinv, y16, N);
        k_bagg1      <<<NB, 512, 0, stream>>>(pairs, gbase, y16, (const float2*)x,
                                              dinv, W1, b1, W2, hp2full, hp01, h2, N);
        k_bagg2a     <<<NB, 512, 0, stream>>>(pairs, gbase, hp01, hp2full, part01, N);
        k_bagg2b     <<<NB, 512, 0, stream>>>(pairs, gbase, h2, hp2full, part01, dinv,
                                              b2, W3, b3, W4, b4, W5, b5,
                                              (float*)d_out, N);
        return;
    }

    // -------- fallback: global counting-sort CSR (fp32) --------
    const int nScanBlocks = (N + SCAN_E - 1) / SCAN_E;
    size_t need2 = (size_t)N * 44 + (size_t)E * 4 + (size_t)nScanBlocks * 4 + 256;
    if (ws_size >= need2 && nScanBlocks <= NT * 4) {
        float4* hp1  = (float4*)ws;
        float4* hp2  = (float4*)(ws + (size_t)N * 16);
        int*    ss   = (int*)   (ws + (size_t)N * 32);
        int*    deg  = (int*)   (ws + (size_t)N * 32 + (size_t)E * 4);
        int*    row  = (int*)   (ws + (size_t)N * 36 + (size_t)E * 4);
        float*  dinv = (float*) (ws + (size_t)N * 40 + (size_t)E * 4);
        int*    bsum = (int*)   (ws + (size_t)N * 44 + (size_t)E * 4);

        hipMemsetAsync(deg, 0, (size_t)N * 4, stream);
        k_deg     <<<gbE, NT, 0, stream>>>(dst, deg, E);
        k_scan1   <<<nScanBlocks, NT, 0, stream>>>(deg, row, bsum, N);
        k_scan2   <<<1, NT, 0, stream>>>(bsum, nScanBlocks);
        k_scan3   <<<nScanBlocks, NT, 0, stream>>>(row, bsum, N);
        k_node1_fb<<<gbN, NT, 0, stream>>>((const float2*)x, deg, W1, dinv, hp1, N);
        k_scatter <<<gbE, NT, 0, stream>>>(src, dst, row, ss, E);
        k_aggf1_fb<<<gbN, NT, 0, stream>>>(row, ss, hp1, dinv, b1, W2, hp2, N);
        k_aggf2_fb<<<gbN, NT, 0, stream>>>(row, ss, hp2, dinv, b2, W3, b3, W4, b4,
                                           W5, b5, (float*)d_out, N);
    }
}